// Round 5
// baseline (954.477 us; speedup 1.0000x reference)
//
#include <hip/hip_runtime.h>
#include <hip/hip_bf16.h>
#include <cmath>

#define NNODES 50000
#define NEDGES 800000
#define IND    512
#define HD     128
#define CD     64

typedef __bf16 bf16x8 __attribute__((ext_vector_type(8)));
typedef float  f32x4  __attribute__((ext_vector_type(4)));

// ---------------- workspace layout (byte offsets) ----------------
// xb (bf16 50000x512, 51.2MB) dead after G1 -> reused for xj + hid
static const size_t XB_B   = 0;           // bf16 50000x512
static const size_t XJ_B   = 0;           // bf16 50000x256 (after xb dead)
static const size_t HID_B  = 25600000;    // bf16 50000x128
static const size_t H1_B   = 51200000;    // bf16 50000x512
static const size_t XW_B   = 102400000;   // bf16 50000x128
static const size_t H2_B   = 115200000;   // bf16 50000x64
static const size_t LG_B   = 121600000;   // bf16 50000x64
static const size_t PE_B   = 128000000;   // bf16 50000x64
static const size_t WT_B   = 134400000;   // transposed bf16 weights (~0.9MB)
static const size_t CSRR_B = 135300000;   // int 800000 (csr row index)
static const size_t EWC_B  = 138500000;   // fp32 800000 (ew in CSR order; normalized in place)
static const size_t CSRW_B = 141700000;   // fp32 800000 (final edge weight)
static const size_t CNT_B  = 144900000;   // int 50000   (zero block start)
static const size_t S_B    = 145100000;   // 2 doubles
static const size_t ZERO_BYTES = 200016;  // cnt + S
static const size_t RP_B   = 145100016;   // int 50001
static const size_t WOFF_B = 145300020;   // int 50000
static const size_t INCL_B = 145500020;   // int 50000
static const size_t BSUM_B = 145700020;   // int 256
static const size_t ST_B   = 145701044;   // 2 floats
static const size_t DIS_B  = 145701052;   // fp32 50000
// total ~145.9 MB

// weight sub-offsets (bytes within WT_B). Wp1t then Wg0t CONTIGUOUS -> fused
// G1 sees one Bt of shape [640, 512].
static const size_t WP1T_O = 0;       // 512x512
static const size_t WG0T_O = 524288;  // 128x512
static const size_t WP2T_O = 655360;  // 64x512
static const size_t WP3T_O = 720896;  // 64x64
static const size_t P0T_O  = 729088;  // 64x64 (relu(2x) applied)
static const size_t WG1T_O = 737280;  // 128x128
static const size_t WL1T_O = 770048;  // 128x256
static const size_t WL2T_O = 835584;  // 64x128

// ---------------- weight transpose+cast: dst[n*K+k] = cvt(f(src[k*N+n])) ----
struct WD { const float* s; __hip_bfloat16* d; int K; int N; int mode; };
struct WP { WD w[8]; };

__global__ __launch_bounds__(256) void transpose_cast_all(WP p)
{
    WD d = p.w[blockIdx.y];
    int i = blockIdx.x * 256 + threadIdx.x;
    if (i >= d.K * d.N) return;
    int k = i % d.K, n = i / d.K;
    float v = d.s[(size_t)k * d.N + n];
    if (d.mode) v = fmaxf(2.f * v, 0.f);
    d.d[i] = __float2bfloat16(v);
}

// ---------------- cast x -> bf16 (8 elems/thread) --------------------------
__global__ __launch_bounds__(256) void cast_x_kernel(
    const float* __restrict__ x, __hip_bfloat16* __restrict__ xb, long n)
{
    long i = ((long)blockIdx.x * 256 + threadIdx.x) * 8;
    if (i >= n) return;
    float4 a = *(const float4*)(x + i);
    float4 b = *(const float4*)(x + i + 4);
    __hip_bfloat16 o[8] __attribute__((aligned(16)));
    o[0] = __float2bfloat16(a.x); o[1] = __float2bfloat16(a.y);
    o[2] = __float2bfloat16(a.z); o[3] = __float2bfloat16(a.w);
    o[4] = __float2bfloat16(b.x); o[5] = __float2bfloat16(b.y);
    o[6] = __float2bfloat16(b.z); o[7] = __float2bfloat16(b.w);
    *(int4*)(xb + i) = *(const int4*)o;
}

// ---------------- bf16 MFMA GEMM: C = act(A[M,K] @ Bt[N,K]^T + bias) -------
// BM=128, 4 waves, wave tile 64 x WN, BN = 2*WN. K%32==0, N%BN==0.
// Blocks XCD-swizzled: the NC col-tiles of one row strip share lin%8.
// splitN: cols >= splitN go to Cout2 (bf16, ld ldc2, no bias, no relu).
template<int BN, int WN>
__global__ __launch_bounds__(256) void gemm_mfma(
    const __hip_bfloat16* __restrict__ A, int lda,
    const __hip_bfloat16* __restrict__ Bt, int ldb,
    const float* __restrict__ bias,
    void* __restrict__ Cout, int ldc,
    void* __restrict__ Cout2, int ldc2, int splitN,
    int M, int K, int do_relu, int out_bf16)
{
    constexpr int BF = WN / 16;
    constexpr int BPASS = BN / 64;
    __shared__ __bf16 As[128 * 40];            // [128 rows][32 k + 8 pad]
    __shared__ __bf16 Bs[BN * 40];

    const int NC = gridDim.x, NR = gridDim.y;
    int g = blockIdx.y * NC + blockIdx.x;
    int per = NC * 8;
    int nfull = (NR >> 3) * per;
    int rowt, colt;
    if (g < nfull) {
        int grp = g / per, rem = g % per;
        rowt = grp * 8 + (rem & 7);
        colt = rem >> 3;
    } else {
        int rem = g - nfull;
        int tail = NR - (NR >> 3) * 8;
        rowt = (NR >> 3) * 8 + rem % tail;
        colt = rem / tail;
    }

    const int t = threadIdx.x;
    const int row0 = rowt * 128;
    const int col0 = colt * BN;

    const int wv   = t >> 6;
    const int lane = t & 63;
    const int quad = lane >> 4;
    const int l16  = lane & 15;
    const int wrow = (wv >> 1) * 64;
    const int wcol = (wv & 1) * WN;

    f32x4 acc[4][BF] = {};

    for (int k0 = 0; k0 < K; k0 += 32) {
        #pragma unroll
        for (int p = 0; p < 2; p++) {
            int idx = t + p * 256;
            int r = idx >> 2, kg = (idx & 3) * 8;
            int m = row0 + r;
            int4 v = make_int4(0, 0, 0, 0);
            if (m < M) v = *(const int4*)(A + (size_t)m * lda + k0 + kg);
            *(int4*)&As[r * 40 + kg] = v;
        }
        #pragma unroll
        for (int p = 0; p < BPASS; p++) {
            int idx = t + p * 256;
            int r = idx >> 2, kg = (idx & 3) * 8;
            int4 v = *(const int4*)(Bt + (size_t)(col0 + r) * ldb + k0 + kg);
            *(int4*)&Bs[r * 40 + kg] = v;
        }
        __syncthreads();

        bf16x8 af[4], bfr[BF];
        #pragma unroll
        for (int i = 0; i < 4; i++)
            af[i] = *(const bf16x8*)&As[(wrow + i * 16 + l16) * 40 + quad * 8];
        #pragma unroll
        for (int j = 0; j < BF; j++)
            bfr[j] = *(const bf16x8*)&Bs[(wcol + j * 16 + l16) * 40 + quad * 8];
        #pragma unroll
        for (int i = 0; i < 4; i++)
            #pragma unroll
            for (int j = 0; j < BF; j++)
                acc[i][j] = __builtin_amdgcn_mfma_f32_16x16x32_bf16(af[i], bfr[j], acc[i][j], 0, 0, 0);
        __syncthreads();
    }

    #pragma unroll
    for (int i = 0; i < 4; i++) {
        #pragma unroll
        for (int j = 0; j < BF; j++) {
            int n = col0 + wcol + j * 16 + l16;
            bool second = (n >= splitN);
            float bv = (!second && bias) ? bias[n] : 0.f;
            #pragma unroll
            for (int reg = 0; reg < 4; reg++) {
                int m = row0 + wrow + i * 16 + quad * 4 + reg;
                if (m >= M) continue;
                float v = acc[i][j][reg] + bv;
                if (do_relu && !second) v = fmaxf(v, 0.f);
                if (second)
                    ((__hip_bfloat16*)Cout2)[(size_t)m * ldc2 + (n - splitN)] = __float2bfloat16(v);
                else if (out_bf16)
                    ((__hip_bfloat16*)Cout)[(size_t)m * ldc + n] = __float2bfloat16(v);
                else
                    ((float*)Cout)[(size_t)m * ldc + n] = v;
            }
        }
    }
}

// ---------------- CSR build (indices only) ---------------------------------
__global__ __launch_bounds__(256) void count_kernel(
    const int* __restrict__ ei, int* __restrict__ cnt)
{
    int e = blockIdx.x * 256 + threadIdx.x;
    if (e >= NEDGES) return;
    atomicAdd(&cnt[ei[NEDGES + e]], 1);
}

__global__ __launch_bounds__(256) void scan1_kernel(
    const int* __restrict__ cnt, int* __restrict__ incl, int* __restrict__ bsum)
{
    __shared__ int s[256];
    int t = threadIdx.x;
    int i = blockIdx.x * 256 + t;
    int v = (i < NNODES) ? cnt[i] : 0;
    s[t] = v;
    __syncthreads();
    for (int off = 1; off < 256; off <<= 1) {
        int u = (t >= off) ? s[t - off] : 0;
        __syncthreads();
        s[t] += u;
        __syncthreads();
    }
    if (i < NNODES) incl[i] = s[t];
    if (t == 255) bsum[blockIdx.x] = s[255];
}

__global__ __launch_bounds__(256) void scan2_kernel(int* __restrict__ bsum, int nb)
{
    __shared__ int s[256];
    int t = threadIdx.x;
    int v = (t < nb) ? bsum[t] : 0;
    s[t] = v;
    __syncthreads();
    for (int off = 1; off < 256; off <<= 1) {
        int u = (t >= off) ? s[t - off] : 0;
        __syncthreads();
        s[t] += u;
        __syncthreads();
    }
    if (t < nb) bsum[t] = s[t] - v;   // exclusive block offset
}

__global__ __launch_bounds__(256) void scan3_kernel(
    const int* __restrict__ cnt, const int* __restrict__ incl,
    const int* __restrict__ bsum, int* __restrict__ rowptr, int* __restrict__ woff)
{
    int i = blockIdx.x * 256 + threadIdx.x;
    if (i >= NNODES) return;
    int off = bsum[blockIdx.x];
    int r = incl[i] - cnt[i] + off;
    rowptr[i] = r;
    woff[i] = r;
    if (i == NNODES - 1) rowptr[NNODES] = incl[i] + off;
}

__global__ __launch_bounds__(256) void scatter_idx_kernel(
    const int* __restrict__ ei, int* __restrict__ woff, int* __restrict__ csr_row)
{
    int e = blockIdx.x * 256 + threadIdx.x;
    if (e >= NEDGES) return;
    int r = ei[e];
    int c = ei[NEDGES + e];
    int p = atomicAdd(&woff[c], 1);
    csr_row[p] = r;
}

// ---------------- edge weight in CSR order ---------------------------------
// one wave per node: pe[n] loaded once (wave-broadcast), lg[row] gathered.
__global__ __launch_bounds__(256) void edge_ew_csr(
    const __hip_bfloat16* __restrict__ lg, const __hip_bfloat16* __restrict__ pe,
    const int* __restrict__ rowptr, const int* __restrict__ csr_row,
    float* __restrict__ ew_csr, double* __restrict__ S)
{
    const int wv = threadIdx.x >> 6, lane = threadIdx.x & 63;
    const int n = blockIdx.x * 4 + wv;
    double s1 = 0.0, s2 = 0.0;
    if (n < NNODES) {
        bf16x8 pcv[8];
        const bf16x8* pp = (const bf16x8*)(pe + (size_t)n * CD);
        #pragma unroll
        for (int k = 0; k < 8; k++) pcv[k] = pp[k];
        int s = rowptr[n], e = rowptr[n + 1];
        for (int j = s + lane; j < e; j += 64) {
            int r = csr_row[j];
            const bf16x8* lr = (const bf16x8*)(lg + (size_t)r * CD);
            float acc = 0.f;
            #pragma unroll
            for (int k = 0; k < 8; k++) {
                bf16x8 a = lr[k];
                #pragma unroll
                for (int u = 0; u < 8; u++)
                    acc += (float)a[u] * (float)pcv[k][u];
            }
            ew_csr[j] = acc;
            s1 += acc; s2 += (double)acc * (double)acc;
        }
    }
    #pragma unroll
    for (int off = 32; off > 0; off >>= 1) {
        s1 += __shfl_down(s1, off);
        s2 += __shfl_down(s2, off);
    }
    __shared__ double sh1[4], sh2[4];
    if (lane == 0) { sh1[wv] = s1; sh2[wv] = s2; }
    __syncthreads();
    if (threadIdx.x == 0) {
        atomicAdd(&S[0], sh1[0] + sh1[1] + sh1[2] + sh1[3]);
        atomicAdd(&S[1], sh2[0] + sh2[1] + sh2[2] + sh2[3]);
    }
}

__global__ void stats_kernel(const double* __restrict__ S, float* __restrict__ st)
{
    double E = (double)NEDGES;
    double mean = S[0] / E;
    double var = (S[1] - S[0] * S[0] / E) / (E - 1.0);
    st[0] = (float)mean;
    st[1] = (float)sqrt(1e-4 / var);
}

// per node: normalize segment in place, deg = segment sum, dis = rsqrt(deg+1)
__global__ __launch_bounds__(256) void norm_deg_kernel(
    const int* __restrict__ rowptr, float* __restrict__ ew_csr,
    const float* __restrict__ st, float* __restrict__ dis)
{
    int n = blockIdx.x * 256 + threadIdx.x;
    if (n >= NNODES) return;
    float mean = st[0], alpha = st[1];
    int s = rowptr[n], e = rowptr[n + 1];
    float sum = 0.f;
    for (int j = s; j < e; j++) {
        float w = (ew_csr[j] - mean) * alpha + 1.0f;
        ew_csr[j] = w;
        sum += w;
    }
    float d = sum + 1.0f;                       // self-loop weight 1
    dis[n] = (d > 0.f) ? rsqrtf(d) : 0.f;
}

// per node: csr_w[j] = dis[row]*w*dis[n]
__global__ __launch_bounds__(256) void csrw_kernel(
    const int* __restrict__ rowptr, const int* __restrict__ csr_row,
    const float* __restrict__ ew_csr, const float* __restrict__ dis,
    float* __restrict__ csr_w)
{
    int n = blockIdx.x * 256 + threadIdx.x;
    if (n >= NNODES) return;
    float dn = dis[n];
    int s = rowptr[n], e = rowptr[n + 1];
    for (int j = s; j < e; j++)
        csr_w[j] = dis[csr_row[j]] * ew_csr[j] * dn;
}

// ---------------- weighted aggregation (bf16 in, bf16 out, fp32 acc) ------
__global__ __launch_bounds__(128) void agg_kernel(
    const __hip_bfloat16* __restrict__ xw, const float* __restrict__ dis,
    const int* __restrict__ rowptr, const int* __restrict__ csr_row,
    const float* __restrict__ csr_w, const float* __restrict__ bias,
    __hip_bfloat16* __restrict__ out, int ldo)
{
    int n = blockIdx.x;
    int f = threadIdx.x;
    float dn = dis[n];
    float acc = dn * dn * __bfloat162float(xw[(size_t)n * HD + f]);
    int s = rowptr[n], e = rowptr[n + 1];
    for (int j = s; j < e; j++) {
        int r = csr_row[j];
        float w = csr_w[j];
        acc += w * __bfloat162float(xw[(size_t)r * HD + f]);
    }
    out[(size_t)n * ldo + f] = __float2bfloat16(fmaxf(acc + bias[f], 0.f));
}

// ---------------- launch --------------------------------------------------
extern "C" void kernel_launch(void* const* d_in, const int* in_sizes, int n_in,
                              void* d_out, int out_size, void* d_ws, size_t ws_size,
                              hipStream_t stream)
{
    const float* x   = (const float*)d_in[0];
    const int*   ei  = (const int*)d_in[1];
    const float* Wp1 = (const float*)d_in[2];
    const float* bp1 = (const float*)d_in[3];
    const float* Wp2 = (const float*)d_in[4];
    const float* bp2 = (const float*)d_in[5];
    const float* Wp3 = (const float*)d_in[6];
    const float* bp3 = (const float*)d_in[7];
    const float* P0  = (const float*)d_in[8];
    const float* Wg0 = (const float*)d_in[9];
    const float* bg0 = (const float*)d_in[10];
    const float* Wg1 = (const float*)d_in[11];
    const float* bg1 = (const float*)d_in[12];
    // d_in[13], d_in[14] = Wg2/bg2: dead in reference
    const float* Wl1 = (const float*)d_in[15];
    const float* bl1 = (const float*)d_in[16];
    const float* Wl2 = (const float*)d_in[17];
    const float* bl2 = (const float*)d_in[18];
    float* out = (float*)d_out;

    char* wsb = (char*)d_ws;
    __hip_bfloat16* xb     = (__hip_bfloat16*)(wsb + XB_B);
    __hip_bfloat16* xj     = (__hip_bfloat16*)(wsb + XJ_B);
    __hip_bfloat16* hid    = (__hip_bfloat16*)(wsb + HID_B);
    __hip_bfloat16* h1     = (__hip_bfloat16*)(wsb + H1_B);
    __hip_bfloat16* xw     = (__hip_bfloat16*)(wsb + XW_B);
    __hip_bfloat16* h2     = (__hip_bfloat16*)(wsb + H2_B);
    __hip_bfloat16* lg     = (__hip_bfloat16*)(wsb + LG_B);
    __hip_bfloat16* pe     = (__hip_bfloat16*)(wsb + PE_B);
    int*            csr_row= (int*)(wsb + CSRR_B);
    float*          ew_csr = (float*)(wsb + EWC_B);
    float*          csr_w  = (float*)(wsb + CSRW_B);
    int*            cnt    = (int*)(wsb + CNT_B);
    double*         S      = (double*)(wsb + S_B);
    int*            rowptr = (int*)(wsb + RP_B);
    int*            woff   = (int*)(wsb + WOFF_B);
    int*            incl   = (int*)(wsb + INCL_B);
    int*            bsum   = (int*)(wsb + BSUM_B);
    float*          st     = (float*)(wsb + ST_B);
    float*          dis    = (float*)(wsb + DIS_B);

    __hip_bfloat16* Wp1t = (__hip_bfloat16*)(wsb + WT_B + WP1T_O);
    __hip_bfloat16* Wg0t = (__hip_bfloat16*)(wsb + WT_B + WG0T_O);
    __hip_bfloat16* Wp2t = (__hip_bfloat16*)(wsb + WT_B + WP2T_O);
    __hip_bfloat16* Wp3t = (__hip_bfloat16*)(wsb + WT_B + WP3T_O);
    __hip_bfloat16* P0t  = (__hip_bfloat16*)(wsb + WT_B + P0T_O);
    __hip_bfloat16* Wg1t = (__hip_bfloat16*)(wsb + WT_B + WG1T_O);
    __hip_bfloat16* Wl1t = (__hip_bfloat16*)(wsb + WT_B + WL1T_O);
    __hip_bfloat16* Wl2t = (__hip_bfloat16*)(wsb + WT_B + WL2T_O);

    const int EB = (NEDGES + 255) / 256;            // 3125
    const int NB = (NNODES + 255) / 256;            // 196
    const int MT = (NNODES + 127) / 128;            // 391 row tiles
    const int BIGN = 1 << 30;

    hipMemsetAsync(wsb + CNT_B, 0, ZERO_BYTES, stream);

    // --- prep: weight transpose+cast, x cast ---
    WP wp;
    wp.w[0] = { Wp1, Wp1t, 512, 512, 0 };
    wp.w[1] = { Wg0, Wg0t, 512, 128, 0 };
    wp.w[2] = { Wp2, Wp2t, 512,  64, 0 };
    wp.w[3] = { Wp3, Wp3t,  64,  64, 0 };
    wp.w[4] = { P0,  P0t,   64,  64, 1 };   // relu(2*P)
    wp.w[5] = { Wg1, Wg1t, 128, 128, 0 };
    wp.w[6] = { Wl1, Wl1t, 256, 128, 0 };
    wp.w[7] = { Wl2, Wl2t, 128,  64, 0 };
    transpose_cast_all<<<dim3(1024, 8), 256, 0, stream>>>(wp);
    cast_x_kernel<<<12500, 256, 0, stream>>>(x, xb, (long)NNODES * IND);

    // --- CSR build (indices only; independent of ew) ---
    count_kernel<<<EB, 256, 0, stream>>>(ei, cnt);
    scan1_kernel<<<NB, 256, 0, stream>>>(cnt, incl, bsum);
    scan2_kernel<<<1, 256, 0, stream>>>(bsum, NB);
    scan3_kernel<<<NB, 256, 0, stream>>>(cnt, incl, bsum, rowptr, woff);
    scatter_idx_kernel<<<EB, 256, 0, stream>>>(ei, woff, csr_row);

    // --- fused G1: [h1 | xw] = xb @ [Wp1 | Wg0]^T  (bf16 A, XCD-swizzled)
    gemm_mfma<128, 64><<<dim3(5, MT), 256, 0, stream>>>(
        xb, 512, Wp1t, 512, bp1, h1, 512, xw, 128, 512, NNODES, 512, 1, 1);

    // --- edge-weight MLP tail ---
    gemm_mfma<64, 32><<<dim3(1, MT), 256, 0, stream>>>(
        h1, 512, Wp2t, 512, bp2, h2, 64, nullptr, 0, BIGN, NNODES, 512, 1, 1);
    gemm_mfma<64, 32><<<dim3(1, MT), 256, 0, stream>>>(
        h2, 64, Wp3t, 64, bp3, lg, 64, nullptr, 0, BIGN, NNODES, 64, 0, 1);
    gemm_mfma<64, 32><<<dim3(1, MT), 256, 0, stream>>>(
        lg, 64, P0t, 64, nullptr, pe, 64, nullptr, 0, BIGN, NNODES, 64, 0, 1);

    // --- per-edge weights in CSR order + stats ---
    edge_ew_csr<<<(NNODES + 3) / 4, 256, 0, stream>>>(lg, pe, rowptr, csr_row, ew_csr, S);
    stats_kernel<<<1, 1, 0, stream>>>(S, st);
    norm_deg_kernel<<<NB, 256, 0, stream>>>(rowptr, ew_csr, st, dis);
    csrw_kernel<<<NB, 256, 0, stream>>>(rowptr, csr_row, ew_csr, dis, csr_w);

    // --- GCN layer 0 aggregation (xw from fused G1) ---
    agg_kernel<<<NNODES, HD, 0, stream>>>(xw, dis, rowptr, csr_row, csr_w, bg0, xj, 2 * HD);

    // --- GCN layer 1 ---
    gemm_mfma<64, 32><<<dim3(2, MT), 256, 0, stream>>>(
        xj, 2 * HD, Wg1t, 128, nullptr, xw, 128, nullptr, 0, BIGN, NNODES, 128, 0, 1);
    agg_kernel<<<NNODES, HD, 0, stream>>>(xw, dis, rowptr, csr_row, csr_w, bg1, xj + HD, 2 * HD);

    // --- JK head ---
    gemm_mfma<128, 64><<<dim3(1, MT), 256, 0, stream>>>(
        xj, 2 * HD, Wl1t, 256, bl1, hid, 128, nullptr, 0, BIGN, NNODES, 256, 1, 1);
    gemm_mfma<64, 32><<<dim3(1, MT), 256, 0, stream>>>(
        hid, 128, Wl2t, 128, bl2, out, 64, nullptr, 0, BIGN, NNODES, 128, 0, 0);
}

// Round 7
// 735.531 us; speedup vs baseline: 1.2977x; 1.2977x over previous
//
#include <hip/hip_runtime.h>
#include <hip/hip_bf16.h>
#include <cmath>

#define NNODES 50000
#define NEDGES 800000
#define IND    512
#define HD     128
#define CD     64

typedef __bf16 bf16x8 __attribute__((ext_vector_type(8)));
typedef float  f32x4  __attribute__((ext_vector_type(4)));

// ---------------- workspace layout (byte offsets) ----------------
// xb (bf16 50000x512, 51.2MB) dead after G1 -> reused for xj + hid
static const size_t XB_B   = 0;           // bf16 50000x512
static const size_t XJ_B   = 0;           // bf16 50000x256 (after xb dead)
static const size_t HID_B  = 25600000;    // bf16 50000x128 (JK head, late)
static const size_t H1_B   = 51200000;    // bf16 50000x512
static const size_t XW_B   = 102400000;   // bf16 50000x128
static const size_t H2_B   = 115200000;   // bf16 50000x64
static const size_t LG_B   = 121600000;   // bf16 50000x64
static const size_t PE_B   = 128000000;   // bf16 50000x64
static const size_t WT_B   = 134400000;   // transposed bf16 weights (~0.9MB)
static const size_t CSRR_B = 135300000;   // int 800000 (csr row index)
static const size_t EWC_B  = 138500000;   // fp32 800000 (ew in CSR order; normalized in place)
// csr_col overlays csr_w: csr_col written by scatter, last read by edge_ew_lin;
// csr_w first written by csrw_kernel which runs strictly AFTER edge_ew_lin.
static const size_t CSRW_B = 141700000;   // int csr_col -> then fp32 csr_w
static const size_t CNT_B  = 144900000;   // int 50000   (zero block start)
static const size_t S_B    = 145100000;   // 2 doubles
static const size_t ZERO_BYTES = 200016;  // cnt + S
static const size_t RP_B   = 145100016;   // int 50001
static const size_t WOFF_B = 145300020;   // int 50000
static const size_t INCL_B = 145500020;   // int 50000
static const size_t BSUM_B = 145700020;   // int 256
static const size_t ST_B   = 145701044;   // 2 floats
static const size_t DIS_B  = 145701052;   // fp32 50000
// total ~145.9 MB

// weight sub-offsets (bytes within WT_B). Wp1t then Wg0t CONTIGUOUS -> fused
// G1 sees one Bt of shape [640, 512].
static const size_t WP1T_O = 0;       // 512x512
static const size_t WG0T_O = 524288;  // 128x512
static const size_t WP2T_O = 655360;  // 64x512
static const size_t WP3T_O = 720896;  // 64x64
static const size_t P0T_O  = 729088;  // 64x64 (relu(2x) applied)
static const size_t WG1T_O = 737280;  // 128x128
static const size_t WL1T_O = 770048;  // 128x256
static const size_t WL2T_O = 835584;  // 64x128

// ---------------- weight transpose+cast: dst[n*K+k] = cvt(f(src[k*N+n])) ----
struct WD { const float* s; __hip_bfloat16* d; int K; int N; int mode; };
struct WP { WD w[8]; };

__global__ __launch_bounds__(256) void transpose_cast_all(WP p)
{
    WD d = p.w[blockIdx.y];
    int i = blockIdx.x * 256 + threadIdx.x;
    if (i >= d.K * d.N) return;
    int k = i % d.K, n = i / d.K;
    float v = d.s[(size_t)k * d.N + n];
    if (d.mode) v = fmaxf(2.f * v, 0.f);
    d.d[i] = __float2bfloat16(v);
}

// ---------------- cast x -> bf16 (8 elems/thread) --------------------------
__global__ __launch_bounds__(256) void cast_x_kernel(
    const float* __restrict__ x, __hip_bfloat16* __restrict__ xb, long n)
{
    long i = ((long)blockIdx.x * 256 + threadIdx.x) * 8;
    if (i >= n) return;
    float4 a = *(const float4*)(x + i);
    float4 b = *(const float4*)(x + i + 4);
    __hip_bfloat16 o[8] __attribute__((aligned(16)));
    o[0] = __float2bfloat16(a.x); o[1] = __float2bfloat16(a.y);
    o[2] = __float2bfloat16(a.z); o[3] = __float2bfloat16(a.w);
    o[4] = __float2bfloat16(b.x); o[5] = __float2bfloat16(b.y);
    o[6] = __float2bfloat16(b.z); o[7] = __float2bfloat16(b.w);
    *(int4*)(xb + i) = *(const int4*)o;
}

// ---------------- bf16 MFMA GEMM: C = act(A[M,K] @ Bt[N,K]^T + bias) -------
// BM=128, 4 waves, wave tile 64 x WN, BN = 2*WN. K%32==0, N%BN==0.
// Blocks XCD-swizzled: the NC col-tiles of one row strip share lin%8.
// splitN: cols >= splitN go to Cout2 (bf16, ld ldc2, no bias, no relu).
template<int BN, int WN>
__global__ __launch_bounds__(256) void gemm_mfma(
    const __hip_bfloat16* __restrict__ A, int lda,
    const __hip_bfloat16* __restrict__ Bt, int ldb,
    const float* __restrict__ bias,
    void* __restrict__ Cout, int ldc,
    void* __restrict__ Cout2, int ldc2, int splitN,
    int M, int K, int do_relu, int out_bf16)
{
    constexpr int BF = WN / 16;
    constexpr int BPASS = BN / 64;
    __shared__ __bf16 As[128 * 40];            // [128 rows][32 k + 8 pad]
    __shared__ __bf16 Bs[BN * 40];

    const int NC = gridDim.x, NR = gridDim.y;
    int g = blockIdx.y * NC + blockIdx.x;
    int per = NC * 8;
    int nfull = (NR >> 3) * per;
    int rowt, colt;
    if (g < nfull) {
        int grp = g / per, rem = g % per;
        rowt = grp * 8 + (rem & 7);
        colt = rem >> 3;
    } else {
        int rem = g - nfull;
        int tail = NR - (NR >> 3) * 8;
        rowt = (NR >> 3) * 8 + rem % tail;
        colt = rem / tail;
    }

    const int t = threadIdx.x;
    const int row0 = rowt * 128;
    const int col0 = colt * BN;

    const int wv   = t >> 6;
    const int lane = t & 63;
    const int quad = lane >> 4;
    const int l16  = lane & 15;
    const int wrow = (wv >> 1) * 64;
    const int wcol = (wv & 1) * WN;

    f32x4 acc[4][BF] = {};

    for (int k0 = 0; k0 < K; k0 += 32) {
        #pragma unroll
        for (int p = 0; p < 2; p++) {
            int idx = t + p * 256;
            int r = idx >> 2, kg = (idx & 3) * 8;
            int m = row0 + r;
            int4 v = make_int4(0, 0, 0, 0);
            if (m < M) v = *(const int4*)(A + (size_t)m * lda + k0 + kg);
            *(int4*)&As[r * 40 + kg] = v;
        }
        #pragma unroll
        for (int p = 0; p < BPASS; p++) {
            int idx = t + p * 256;
            int r = idx >> 2, kg = (idx & 3) * 8;
            int4 v = *(const int4*)(Bt + (size_t)(col0 + r) * ldb + k0 + kg);
            *(int4*)&Bs[r * 40 + kg] = v;
        }
        __syncthreads();

        bf16x8 af[4], bfr[BF];
        #pragma unroll
        for (int i = 0; i < 4; i++)
            af[i] = *(const bf16x8*)&As[(wrow + i * 16 + l16) * 40 + quad * 8];
        #pragma unroll
        for (int j = 0; j < BF; j++)
            bfr[j] = *(const bf16x8*)&Bs[(wcol + j * 16 + l16) * 40 + quad * 8];
        #pragma unroll
        for (int i = 0; i < 4; i++)
            #pragma unroll
            for (int j = 0; j < BF; j++)
                acc[i][j] = __builtin_amdgcn_mfma_f32_16x16x32_bf16(af[i], bfr[j], acc[i][j], 0, 0, 0);
        __syncthreads();
    }

    #pragma unroll
    for (int i = 0; i < 4; i++) {
        #pragma unroll
        for (int j = 0; j < BF; j++) {
            int n = col0 + wcol + j * 16 + l16;
            bool second = (n >= splitN);
            float bv = (!second && bias) ? bias[n] : 0.f;
            #pragma unroll
            for (int reg = 0; reg < 4; reg++) {
                int m = row0 + wrow + i * 16 + quad * 4 + reg;
                if (m >= M) continue;
                float v = acc[i][j][reg] + bv;
                if (do_relu && !second) v = fmaxf(v, 0.f);
                if (second)
                    ((__hip_bfloat16*)Cout2)[(size_t)m * ldc2 + (n - splitN)] = __float2bfloat16(v);
                else if (out_bf16)
                    ((__hip_bfloat16*)Cout)[(size_t)m * ldc + n] = __float2bfloat16(v);
                else
                    ((float*)Cout)[(size_t)m * ldc + n] = v;
            }
        }
    }
}

// ---------------- CSR build (indices only) ---------------------------------
__global__ __launch_bounds__(256) void count_kernel(
    const int* __restrict__ ei, int* __restrict__ cnt)
{
    int e = blockIdx.x * 256 + threadIdx.x;
    if (e >= NEDGES) return;
    atomicAdd(&cnt[ei[NEDGES + e]], 1);
}

__global__ __launch_bounds__(256) void scan1_kernel(
    const int* __restrict__ cnt, int* __restrict__ incl, int* __restrict__ bsum)
{
    __shared__ int s[256];
    int t = threadIdx.x;
    int i = blockIdx.x * 256 + t;
    int v = (i < NNODES) ? cnt[i] : 0;
    s[t] = v;
    __syncthreads();
    for (int off = 1; off < 256; off <<= 1) {
        int u = (t >= off) ? s[t - off] : 0;
        __syncthreads();
        s[t] += u;
        __syncthreads();
    }
    if (i < NNODES) incl[i] = s[t];
    if (t == 255) bsum[blockIdx.x] = s[255];
}

__global__ __launch_bounds__(256) void scan2_kernel(int* __restrict__ bsum, int nb)
{
    __shared__ int s[256];
    int t = threadIdx.x;
    int v = (t < nb) ? bsum[t] : 0;
    s[t] = v;
    __syncthreads();
    for (int off = 1; off < 256; off <<= 1) {
        int u = (t >= off) ? s[t - off] : 0;
        __syncthreads();
        s[t] += u;
        __syncthreads();
    }
    if (t < nb) bsum[t] = s[t] - v;   // exclusive block offset
}

__global__ __launch_bounds__(256) void scan3_kernel(
    const int* __restrict__ cnt, const int* __restrict__ incl,
    const int* __restrict__ bsum, int* __restrict__ rowptr, int* __restrict__ woff)
{
    int i = blockIdx.x * 256 + threadIdx.x;
    if (i >= NNODES) return;
    int off = bsum[blockIdx.x];
    int r = incl[i] - cnt[i] + off;
    rowptr[i] = r;
    woff[i] = r;
    if (i == NNODES - 1) rowptr[NNODES] = incl[i] + off;
}

__global__ __launch_bounds__(256) void scatter_idx_kernel(
    const int* __restrict__ ei, int* __restrict__ woff,
    int* __restrict__ csr_row, int* __restrict__ csr_col)
{
    int e = blockIdx.x * 256 + threadIdx.x;
    if (e >= NEDGES) return;
    int r = ei[e];
    int c = ei[NEDGES + e];
    int p = atomicAdd(&woff[c], 1);
    csr_row[p] = r;
    csr_col[p] = c;
}

// ---------------- edge weight, thread-per-edge in CSR order ----------------
// consecutive threads walk pe rows sequentially (L2-friendly); lg gathered.
__global__ __launch_bounds__(256) void edge_ew_lin(
    const __hip_bfloat16* __restrict__ lg, const __hip_bfloat16* __restrict__ pe,
    const int* __restrict__ csr_row, const int* __restrict__ csr_col,
    float* __restrict__ ew_csr, double* __restrict__ S)
{
    const int tid = threadIdx.x;
    const int e = blockIdx.x * 256 + tid;
    double v = 0.0, v2 = 0.0;
    if (e < NEDGES) {
        int r = csr_row[e];
        int c = csr_col[e];
        const bf16x8* lr = (const bf16x8*)(lg + (size_t)r * CD);
        const bf16x8* pc = (const bf16x8*)(pe + (size_t)c * CD);
        float acc = 0.f;
        #pragma unroll
        for (int k = 0; k < CD / 8; k++) {
            bf16x8 a = lr[k], b = pc[k];
            #pragma unroll
            for (int u = 0; u < 8; u++)
                acc += (float)a[u] * (float)b[u];
        }
        ew_csr[e] = acc;
        v = acc; v2 = (double)acc * (double)acc;
    }
    __shared__ double s1[256], s2[256];
    s1[tid] = v; s2[tid] = v2;
    __syncthreads();
    for (int s = 128; s > 0; s >>= 1) {
        if (tid < s) { s1[tid] += s1[tid + s]; s2[tid] += s2[tid + s]; }
        __syncthreads();
    }
    if (tid == 0) {
        atomicAdd(&S[0], s1[0]);
        atomicAdd(&S[1], s2[0]);
    }
}

__global__ void stats_kernel(const double* __restrict__ S, float* __restrict__ st)
{
    double E = (double)NEDGES;
    double mean = S[0] / E;
    double var = (S[1] - S[0] * S[0] / E) / (E - 1.0);
    st[0] = (float)mean;
    st[1] = (float)sqrt(1e-4 / var);
}

// per node: normalize segment in place, deg = segment sum, dis = rsqrt(deg+1)
__global__ __launch_bounds__(256) void norm_deg_kernel(
    const int* __restrict__ rowptr, float* __restrict__ ew_csr,
    const float* __restrict__ st, float* __restrict__ dis)
{
    int n = blockIdx.x * 256 + threadIdx.x;
    if (n >= NNODES) return;
    float mean = st[0], alpha = st[1];
    int s = rowptr[n], e = rowptr[n + 1];
    float sum = 0.f;
    for (int j = s; j < e; j++) {
        float w = (ew_csr[j] - mean) * alpha + 1.0f;
        ew_csr[j] = w;
        sum += w;
    }
    float d = sum + 1.0f;                       // self-loop weight 1
    dis[n] = (d > 0.f) ? rsqrtf(d) : 0.f;
}

// per node: csr_w[j] = dis[row]*w*dis[n]  (csr_w overlays the dead csr_col)
__global__ __launch_bounds__(256) void csrw_kernel(
    const int* __restrict__ rowptr, const int* __restrict__ csr_row,
    const float* __restrict__ ew_csr, const float* __restrict__ dis,
    float* __restrict__ csr_w)
{
    int n = blockIdx.x * 256 + threadIdx.x;
    if (n >= NNODES) return;
    float dn = dis[n];
    int s = rowptr[n], e = rowptr[n + 1];
    for (int j = s; j < e; j++)
        csr_w[j] = dis[csr_row[j]] * ew_csr[j] * dn;
}

// ---------------- weighted aggregation (bf16 in, bf16 out, fp32 acc) ------
__global__ __launch_bounds__(128) void agg_kernel(
    const __hip_bfloat16* __restrict__ xw, const float* __restrict__ dis,
    const int* __restrict__ rowptr, const int* __restrict__ csr_row,
    const float* __restrict__ csr_w, const float* __restrict__ bias,
    __hip_bfloat16* __restrict__ out, int ldo)
{
    int n = blockIdx.x;
    int f = threadIdx.x;
    float dn = dis[n];
    float acc = dn * dn * __bfloat162float(xw[(size_t)n * HD + f]);
    int s = rowptr[n], e = rowptr[n + 1];
    for (int j = s; j < e; j++) {
        int r = csr_row[j];
        float w = csr_w[j];
        acc += w * __bfloat162float(xw[(size_t)r * HD + f]);
    }
    out[(size_t)n * ldo + f] = __float2bfloat16(fmaxf(acc + bias[f], 0.f));
}

// ---------------- launch --------------------------------------------------
extern "C" void kernel_launch(void* const* d_in, const int* in_sizes, int n_in,
                              void* d_out, int out_size, void* d_ws, size_t ws_size,
                              hipStream_t stream)
{
    const float* x   = (const float*)d_in[0];
    const int*   ei  = (const int*)d_in[1];
    const float* Wp1 = (const float*)d_in[2];
    const float* bp1 = (const float*)d_in[3];
    const float* Wp2 = (const float*)d_in[4];
    const float* bp2 = (const float*)d_in[5];
    const float* Wp3 = (const float*)d_in[6];
    const float* bp3 = (const float*)d_in[7];
    const float* P0  = (const float*)d_in[8];
    const float* Wg0 = (const float*)d_in[9];
    const float* bg0 = (const float*)d_in[10];
    const float* Wg1 = (const float*)d_in[11];
    const float* bg1 = (const float*)d_in[12];
    // d_in[13], d_in[14] = Wg2/bg2: dead in reference
    const float* Wl1 = (const float*)d_in[15];
    const float* bl1 = (const float*)d_in[16];
    const float* Wl2 = (const float*)d_in[17];
    const float* bl2 = (const float*)d_in[18];
    float* out = (float*)d_out;

    char* wsb = (char*)d_ws;
    __hip_bfloat16* xb     = (__hip_bfloat16*)(wsb + XB_B);
    __hip_bfloat16* xj     = (__hip_bfloat16*)(wsb + XJ_B);
    __hip_bfloat16* hid    = (__hip_bfloat16*)(wsb + HID_B);
    __hip_bfloat16* h1     = (__hip_bfloat16*)(wsb + H1_B);
    __hip_bfloat16* xw     = (__hip_bfloat16*)(wsb + XW_B);
    __hip_bfloat16* h2     = (__hip_bfloat16*)(wsb + H2_B);
    __hip_bfloat16* lg     = (__hip_bfloat16*)(wsb + LG_B);
    __hip_bfloat16* pe     = (__hip_bfloat16*)(wsb + PE_B);
    int*            csr_row= (int*)(wsb + CSRR_B);
    float*          ew_csr = (float*)(wsb + EWC_B);
    int*            csr_col= (int*)(wsb + CSRW_B);   // overlays csr_w (dead until csrw_kernel)
    float*          csr_w  = (float*)(wsb + CSRW_B);
    int*            cnt    = (int*)(wsb + CNT_B);
    double*         S      = (double*)(wsb + S_B);
    int*            rowptr = (int*)(wsb + RP_B);
    int*            woff   = (int*)(wsb + WOFF_B);
    int*            incl   = (int*)(wsb + INCL_B);
    int*            bsum   = (int*)(wsb + BSUM_B);
    float*          st     = (float*)(wsb + ST_B);
    float*          dis    = (float*)(wsb + DIS_B);

    __hip_bfloat16* Wp1t = (__hip_bfloat16*)(wsb + WT_B + WP1T_O);
    __hip_bfloat16* Wg0t = (__hip_bfloat16*)(wsb + WT_B + WG0T_O);
    __hip_bfloat16* Wp2t = (__hip_bfloat16*)(wsb + WT_B + WP2T_O);
    __hip_bfloat16* Wp3t = (__hip_bfloat16*)(wsb + WT_B + WP3T_O);
    __hip_bfloat16* P0t  = (__hip_bfloat16*)(wsb + WT_B + P0T_O);
    __hip_bfloat16* Wg1t = (__hip_bfloat16*)(wsb + WT_B + WG1T_O);
    __hip_bfloat16* Wl1t = (__hip_bfloat16*)(wsb + WT_B + WL1T_O);
    __hip_bfloat16* Wl2t = (__hip_bfloat16*)(wsb + WT_B + WL2T_O);

    const int EB = (NEDGES + 255) / 256;            // 3125
    const int NB = (NNODES + 255) / 256;            // 196
    const int MT = (NNODES + 127) / 128;            // 391 row tiles
    const int BIGN = 1 << 30;

    hipMemsetAsync(wsb + CNT_B, 0, ZERO_BYTES, stream);

    // --- prep: weight transpose+cast, x cast ---
    WP wp;
    wp.w[0] = { Wp1, Wp1t, 512, 512, 0 };
    wp.w[1] = { Wg0, Wg0t, 512, 128, 0 };
    wp.w[2] = { Wp2, Wp2t, 512,  64, 0 };
    wp.w[3] = { Wp3, Wp3t,  64,  64, 0 };
    wp.w[4] = { P0,  P0t,   64,  64, 1 };   // relu(2*P)
    wp.w[5] = { Wg1, Wg1t, 128, 128, 0 };
    wp.w[6] = { Wl1, Wl1t, 256, 128, 0 };
    wp.w[7] = { Wl2, Wl2t, 128,  64, 0 };
    transpose_cast_all<<<dim3(1024, 8), 256, 0, stream>>>(wp);
    cast_x_kernel<<<12500, 256, 0, stream>>>(x, xb, (long)NNODES * IND);

    // --- CSR build (indices only; independent of ew) ---
    count_kernel<<<EB, 256, 0, stream>>>(ei, cnt);
    scan1_kernel<<<NB, 256, 0, stream>>>(cnt, incl, bsum);
    scan2_kernel<<<1, 256, 0, stream>>>(bsum, NB);
    scan3_kernel<<<NB, 256, 0, stream>>>(cnt, incl, bsum, rowptr, woff);
    scatter_idx_kernel<<<EB, 256, 0, stream>>>(ei, woff, csr_row, csr_col);

    // --- fused G1: [h1 | xw] = xb @ [Wp1 | Wg0]^T  (bf16 A, XCD-swizzled)
    gemm_mfma<128, 64><<<dim3(5, MT), 256, 0, stream>>>(
        xb, 512, Wp1t, 512, bp1, h1, 512, xw, 128, 512, NNODES, 512, 1, 1);

    // --- edge-weight MLP tail ---
    gemm_mfma<64, 32><<<dim3(1, MT), 256, 0, stream>>>(
        h1, 512, Wp2t, 512, bp2, h2, 64, nullptr, 0, BIGN, NNODES, 512, 1, 1);
    gemm_mfma<64, 32><<<dim3(1, MT), 256, 0, stream>>>(
        h2, 64, Wp3t, 64, bp3, lg, 64, nullptr, 0, BIGN, NNODES, 64, 0, 1);
    gemm_mfma<64, 32><<<dim3(1, MT), 256, 0, stream>>>(
        lg, 64, P0t, 64, nullptr, pe, 64, nullptr, 0, BIGN, NNODES, 64, 0, 1);

    // --- per-edge weights, thread-per-edge in CSR order + stats ---
    edge_ew_lin<<<EB, 256, 0, stream>>>(lg, pe, csr_row, csr_col, ew_csr, S);
    stats_kernel<<<1, 1, 0, stream>>>(S, st);
    norm_deg_kernel<<<NB, 256, 0, stream>>>(rowptr, ew_csr, st, dis);
    csrw_kernel<<<NB, 256, 0, stream>>>(rowptr, csr_row, ew_csr, dis, csr_w);

    // --- GCN layer 0 aggregation (xw from fused G1) ---
    agg_kernel<<<NNODES, HD, 0, stream>>>(xw, dis, rowptr, csr_row, csr_w, bg0, xj, 2 * HD);

    // --- GCN layer 1 ---
    gemm_mfma<64, 32><<<dim3(2, MT), 256, 0, stream>>>(
        xj, 2 * HD, Wg1t, 128, nullptr, xw, 128, nullptr, 0, BIGN, NNODES, 128, 0, 1);
    agg_kernel<<<NNODES, HD, 0, stream>>>(xw, dis, rowptr, csr_row, csr_w, bg1, xj + HD, 2 * HD);

    // --- JK head ---
    gemm_mfma<128, 64><<<dim3(1, MT), 256, 0, stream>>>(
        xj, 2 * HD, Wl1t, 256, bl1, hid, 128, nullptr, 0, BIGN, NNODES, 256, 1, 1);
    gemm_mfma<64, 32><<<dim3(1, MT), 256, 0, stream>>>(
        hid, 128, Wl2t, 128, bl2, out, 64, nullptr, 0, BIGN, NNODES, 128, 0, 0);
}

// Round 8
// 678.885 us; speedup vs baseline: 1.4059x; 1.0834x over previous
//
#include <hip/hip_runtime.h>
#include <hip/hip_bf16.h>
#include <cmath>

#define NNODES 50000
#define NEDGES 800000
#define IND    512
#define HD     128
#define CD     64

typedef __bf16 bf16x8 __attribute__((ext_vector_type(8)));
typedef float  f32x4  __attribute__((ext_vector_type(4)));

// ---------------- workspace layout (byte offsets) ----------------
// xb (bf16 50000x512, 51.2MB) dead after G1 -> reused for xj + hid
static const size_t XB_B   = 0;           // bf16 50000x512
static const size_t XJ_B   = 0;           // bf16 50000x256 (after xb dead)
static const size_t HID_B  = 25600000;    // bf16 50000x128 (JK head, late)
static const size_t H1_B   = 51200000;    // bf16 50000x512
static const size_t XW_B   = 102400000;   // bf16 50000x128
static const size_t H2_B   = 115200000;   // bf16 50000x64
static const size_t LG_B   = 121600000;   // bf16 50000x64
static const size_t PE_B   = 128000000;   // bf16 50000x64
static const size_t WT_B   = 134400000;   // transposed bf16 weights (~0.9MB)
static const size_t CSRR_B = 135300000;   // int 800000 (csr row index)
static const size_t EWC_B  = 138500000;   // fp32 800000 (ew in CSR order; normalized in place)
// csr_col overlays csr_w: csr_col written by scatter, last read by edge_ew_gather;
// csr_w first written by csrw_kernel which runs strictly AFTER edge_ew_gather.
static const size_t CSRW_B = 141700000;   // int csr_col -> then fp32 csr_w
static const size_t CNT_B  = 144900000;   // int 50000   (zero block start)
static const size_t S_B    = 145100000;   // 2 doubles
static const size_t ZERO_BYTES = 200016;  // cnt + S
static const size_t RP_B   = 145100016;   // int 50001
static const size_t WOFF_B = 145300020;   // int 50000
static const size_t INCL_B = 145500020;   // int 50000
static const size_t BSUM_B = 145700020;   // int 256
static const size_t ST_B   = 145701044;   // 2 floats
static const size_t DIS_B  = 145701052;   // fp32 50000
// total ~145.9 MB

// weight sub-offsets (bytes within WT_B). Wp1t then Wg0t CONTIGUOUS -> fused
// G1 sees one Bt of shape [640, 512].
static const size_t WP1T_O = 0;       // 512x512
static const size_t WG0T_O = 524288;  // 128x512
static const size_t WP2T_O = 655360;  // 64x512
static const size_t WP3T_O = 720896;  // 64x64
static const size_t P0T_O  = 729088;  // 64x64 (relu(2x) applied)
static const size_t WG1T_O = 737280;  // 128x128
static const size_t WL1T_O = 770048;  // 128x256
static const size_t WL2T_O = 835584;  // 64x128

// ---------------- weight transpose+cast: dst[n*K+k] = cvt(f(src[k*N+n])) ----
struct WD { const float* s; __hip_bfloat16* d; int K; int N; int mode; };
struct WP { WD w[8]; };

__global__ __launch_bounds__(256) void transpose_cast_all(WP p)
{
    WD d = p.w[blockIdx.y];
    int i = blockIdx.x * 256 + threadIdx.x;
    if (i >= d.K * d.N) return;
    int k = i % d.K, n = i / d.K;
    float v = d.s[(size_t)k * d.N + n];
    if (d.mode) v = fmaxf(2.f * v, 0.f);
    d.d[i] = __float2bfloat16(v);
}

// ---------------- cast x -> bf16 (8 elems/thread) --------------------------
__global__ __launch_bounds__(256) void cast_x_kernel(
    const float* __restrict__ x, __hip_bfloat16* __restrict__ xb, long n)
{
    long i = ((long)blockIdx.x * 256 + threadIdx.x) * 8;
    if (i >= n) return;
    float4 a = *(const float4*)(x + i);
    float4 b = *(const float4*)(x + i + 4);
    __hip_bfloat16 o[8] __attribute__((aligned(16)));
    o[0] = __float2bfloat16(a.x); o[1] = __float2bfloat16(a.y);
    o[2] = __float2bfloat16(a.z); o[3] = __float2bfloat16(a.w);
    o[4] = __float2bfloat16(b.x); o[5] = __float2bfloat16(b.y);
    o[6] = __float2bfloat16(b.z); o[7] = __float2bfloat16(b.w);
    *(int4*)(xb + i) = *(const int4*)o;
}

// ---------------- bf16 MFMA GEMM: C = act(A[M,K] @ Bt[N,K]^T + bias) -------
// BM=128, 4 waves, wave tile 64 x WN, BN = 2*WN. K%32==0, N%BN==0.
// Blocks XCD-swizzled: the NC col-tiles of one row strip share lin%8.
// splitN: cols >= splitN go to Cout2 (bf16, ld ldc2, no bias, no relu).
template<int BN, int WN>
__global__ __launch_bounds__(256) void gemm_mfma(
    const __hip_bfloat16* __restrict__ A, int lda,
    const __hip_bfloat16* __restrict__ Bt, int ldb,
    const float* __restrict__ bias,
    void* __restrict__ Cout, int ldc,
    void* __restrict__ Cout2, int ldc2, int splitN,
    int M, int K, int do_relu, int out_bf16)
{
    constexpr int BF = WN / 16;
    constexpr int BPASS = BN / 64;
    __shared__ __bf16 As[128 * 40];            // [128 rows][32 k + 8 pad]
    __shared__ __bf16 Bs[BN * 40];

    const int NC = gridDim.x, NR = gridDim.y;
    int g = blockIdx.y * NC + blockIdx.x;
    int per = NC * 8;
    int nfull = (NR >> 3) * per;
    int rowt, colt;
    if (g < nfull) {
        int grp = g / per, rem = g % per;
        rowt = grp * 8 + (rem & 7);
        colt = rem >> 3;
    } else {
        int rem = g - nfull;
        int tail = NR - (NR >> 3) * 8;
        rowt = (NR >> 3) * 8 + rem % tail;
        colt = rem / tail;
    }

    const int t = threadIdx.x;
    const int row0 = rowt * 128;
    const int col0 = colt * BN;

    const int wv   = t >> 6;
    const int lane = t & 63;
    const int quad = lane >> 4;
    const int l16  = lane & 15;
    const int wrow = (wv >> 1) * 64;
    const int wcol = (wv & 1) * WN;

    f32x4 acc[4][BF] = {};

    for (int k0 = 0; k0 < K; k0 += 32) {
        #pragma unroll
        for (int p = 0; p < 2; p++) {
            int idx = t + p * 256;
            int r = idx >> 2, kg = (idx & 3) * 8;
            int m = row0 + r;
            int4 v = make_int4(0, 0, 0, 0);
            if (m < M) v = *(const int4*)(A + (size_t)m * lda + k0 + kg);
            *(int4*)&As[r * 40 + kg] = v;
        }
        #pragma unroll
        for (int p = 0; p < BPASS; p++) {
            int idx = t + p * 256;
            int r = idx >> 2, kg = (idx & 3) * 8;
            int4 v = *(const int4*)(Bt + (size_t)(col0 + r) * ldb + k0 + kg);
            *(int4*)&Bs[r * 40 + kg] = v;
        }
        __syncthreads();

        bf16x8 af[4], bfr[BF];
        #pragma unroll
        for (int i = 0; i < 4; i++)
            af[i] = *(const bf16x8*)&As[(wrow + i * 16 + l16) * 40 + quad * 8];
        #pragma unroll
        for (int j = 0; j < BF; j++)
            bfr[j] = *(const bf16x8*)&Bs[(wcol + j * 16 + l16) * 40 + quad * 8];
        #pragma unroll
        for (int i = 0; i < 4; i++)
            #pragma unroll
            for (int j = 0; j < BF; j++)
                acc[i][j] = __builtin_amdgcn_mfma_f32_16x16x32_bf16(af[i], bfr[j], acc[i][j], 0, 0, 0);
        __syncthreads();
    }

    #pragma unroll
    for (int i = 0; i < 4; i++) {
        #pragma unroll
        for (int j = 0; j < BF; j++) {
            int n = col0 + wcol + j * 16 + l16;
            bool second = (n >= splitN);
            float bv = (!second && bias) ? bias[n] : 0.f;
            #pragma unroll
            for (int reg = 0; reg < 4; reg++) {
                int m = row0 + wrow + i * 16 + quad * 4 + reg;
                if (m >= M) continue;
                float v = acc[i][j][reg] + bv;
                if (do_relu && !second) v = fmaxf(v, 0.f);
                if (second)
                    ((__hip_bfloat16*)Cout2)[(size_t)m * ldc2 + (n - splitN)] = __float2bfloat16(v);
                else if (out_bf16)
                    ((__hip_bfloat16*)Cout)[(size_t)m * ldc + n] = __float2bfloat16(v);
                else
                    ((float*)Cout)[(size_t)m * ldc + n] = v;
            }
        }
    }
}

// ---------------- CSR build (indices only) ---------------------------------
__global__ __launch_bounds__(256) void count_kernel(
    const int* __restrict__ ei, int* __restrict__ cnt)
{
    int e = blockIdx.x * 256 + threadIdx.x;
    if (e >= NEDGES) return;
    atomicAdd(&cnt[ei[NEDGES + e]], 1);
}

__global__ __launch_bounds__(256) void scan1_kernel(
    const int* __restrict__ cnt, int* __restrict__ incl, int* __restrict__ bsum)
{
    __shared__ int s[256];
    int t = threadIdx.x;
    int i = blockIdx.x * 256 + t;
    int v = (i < NNODES) ? cnt[i] : 0;
    s[t] = v;
    __syncthreads();
    for (int off = 1; off < 256; off <<= 1) {
        int u = (t >= off) ? s[t - off] : 0;
        __syncthreads();
        s[t] += u;
        __syncthreads();
    }
    if (i < NNODES) incl[i] = s[t];
    if (t == 255) bsum[blockIdx.x] = s[255];
}

__global__ __launch_bounds__(256) void scan2_kernel(int* __restrict__ bsum, int nb)
{
    __shared__ int s[256];
    int t = threadIdx.x;
    int v = (t < nb) ? bsum[t] : 0;
    s[t] = v;
    __syncthreads();
    for (int off = 1; off < 256; off <<= 1) {
        int u = (t >= off) ? s[t - off] : 0;
        __syncthreads();
        s[t] += u;
        __syncthreads();
    }
    if (t < nb) bsum[t] = s[t] - v;   // exclusive block offset
}

__global__ __launch_bounds__(256) void scan3_kernel(
    const int* __restrict__ cnt, const int* __restrict__ incl,
    const int* __restrict__ bsum, int* __restrict__ rowptr, int* __restrict__ woff)
{
    int i = blockIdx.x * 256 + threadIdx.x;
    if (i >= NNODES) return;
    int off = bsum[blockIdx.x];
    int r = incl[i] - cnt[i] + off;
    rowptr[i] = r;
    woff[i] = r;
    if (i == NNODES - 1) rowptr[NNODES] = incl[i] + off;
}

__global__ __launch_bounds__(256) void scatter_idx_kernel(
    const int* __restrict__ ei, int* __restrict__ woff,
    int* __restrict__ csr_row, int* __restrict__ csr_col)
{
    int e = blockIdx.x * 256 + threadIdx.x;
    if (e >= NEDGES) return;
    int r = ei[e];
    int c = ei[NEDGES + e];
    int p = atomicAdd(&woff[c], 1);
    csr_row[p] = r;
    csr_col[p] = c;
}

// ---------------- edge weight: 8 lanes cooperate per edge ------------------
// lane sub (0..7) loads 16B chunk sub of the 128B row -> per load instruction
// a wave touches 8 contiguous 128B segments instead of 64 scattered 16B ones.
__global__ __launch_bounds__(256) void edge_ew_gather(
    const __hip_bfloat16* __restrict__ lg, const __hip_bfloat16* __restrict__ pe,
    const int* __restrict__ csr_row, const int* __restrict__ csr_col,
    float* __restrict__ ew_csr)
{
    const int tid = threadIdx.x;
    const int sub = tid & 7;
    const int e = blockIdx.x * 32 + (tid >> 3);
    if (e >= NEDGES) return;
    int r = csr_row[e];
    int c = csr_col[e];
    bf16x8 a = *(const bf16x8*)(lg + (size_t)r * CD + sub * 8);
    bf16x8 b = *(const bf16x8*)(pe + (size_t)c * CD + sub * 8);
    float acc = 0.f;
    #pragma unroll
    for (int u = 0; u < 8; u++)
        acc += (float)a[u] * (float)b[u];
    acc += __shfl_xor(acc, 1);
    acc += __shfl_xor(acc, 2);
    acc += __shfl_xor(acc, 4);
    if (sub == 0) ew_csr[e] = acc;
}

// grid-stride stats over the dense ew array (sequential read, ~3.2MB)
__global__ __launch_bounds__(256) void ew_stats_kernel(
    const float* __restrict__ ew, double* __restrict__ S)
{
    const int tid = threadIdx.x;
    double s1 = 0.0, s2 = 0.0;
    for (int i = blockIdx.x * 256 + tid; i < NEDGES; i += gridDim.x * 256) {
        float v = ew[i];
        s1 += v; s2 += (double)v * (double)v;
    }
    __shared__ double sh1[256], sh2[256];
    sh1[tid] = s1; sh2[tid] = s2;
    __syncthreads();
    for (int s = 128; s > 0; s >>= 1) {
        if (tid < s) { sh1[tid] += sh1[tid + s]; sh2[tid] += sh2[tid + s]; }
        __syncthreads();
    }
    if (tid == 0) {
        atomicAdd(&S[0], sh1[0]);
        atomicAdd(&S[1], sh2[0]);
    }
}

__global__ void stats_kernel(const double* __restrict__ S, float* __restrict__ st)
{
    double E = (double)NEDGES;
    double mean = S[0] / E;
    double var = (S[1] - S[0] * S[0] / E) / (E - 1.0);
    st[0] = (float)mean;
    st[1] = (float)sqrt(1e-4 / var);
}

// per node: normalize segment in place, deg = segment sum, dis = rsqrt(deg+1)
__global__ __launch_bounds__(256) void norm_deg_kernel(
    const int* __restrict__ rowptr, float* __restrict__ ew_csr,
    const float* __restrict__ st, float* __restrict__ dis)
{
    int n = blockIdx.x * 256 + threadIdx.x;
    if (n >= NNODES) return;
    float mean = st[0], alpha = st[1];
    int s = rowptr[n], e = rowptr[n + 1];
    float sum = 0.f;
    for (int j = s; j < e; j++) {
        float w = (ew_csr[j] - mean) * alpha + 1.0f;
        ew_csr[j] = w;
        sum += w;
    }
    float d = sum + 1.0f;                       // self-loop weight 1
    dis[n] = (d > 0.f) ? rsqrtf(d) : 0.f;
}

// per node: csr_w[j] = dis[row]*w*dis[n]  (csr_w overlays the dead csr_col)
__global__ __launch_bounds__(256) void csrw_kernel(
    const int* __restrict__ rowptr, const int* __restrict__ csr_row,
    const float* __restrict__ ew_csr, const float* __restrict__ dis,
    float* __restrict__ csr_w)
{
    int n = blockIdx.x * 256 + threadIdx.x;
    if (n >= NNODES) return;
    float dn = dis[n];
    int s = rowptr[n], e = rowptr[n + 1];
    for (int j = s; j < e; j++)
        csr_w[j] = dis[csr_row[j]] * ew_csr[j] * dn;
}

// ---------------- weighted aggregation (bf16 in, bf16 out, fp32 acc) ------
__global__ __launch_bounds__(128) void agg_kernel(
    const __hip_bfloat16* __restrict__ xw, const float* __restrict__ dis,
    const int* __restrict__ rowptr, const int* __restrict__ csr_row,
    const float* __restrict__ csr_w, const float* __restrict__ bias,
    __hip_bfloat16* __restrict__ out, int ldo)
{
    int n = blockIdx.x;
    int f = threadIdx.x;
    float dn = dis[n];
    float acc = dn * dn * __bfloat162float(xw[(size_t)n * HD + f]);
    int s = rowptr[n], e = rowptr[n + 1];
    for (int j = s; j < e; j++) {
        int r = csr_row[j];
        float w = csr_w[j];
        acc += w * __bfloat162float(xw[(size_t)r * HD + f]);
    }
    out[(size_t)n * ldo + f] = __float2bfloat16(fmaxf(acc + bias[f], 0.f));
}

// ---------------- launch --------------------------------------------------
extern "C" void kernel_launch(void* const* d_in, const int* in_sizes, int n_in,
                              void* d_out, int out_size, void* d_ws, size_t ws_size,
                              hipStream_t stream)
{
    const float* x   = (const float*)d_in[0];
    const int*   ei  = (const int*)d_in[1];
    const float* Wp1 = (const float*)d_in[2];
    const float* bp1 = (const float*)d_in[3];
    const float* Wp2 = (const float*)d_in[4];
    const float* bp2 = (const float*)d_in[5];
    const float* Wp3 = (const float*)d_in[6];
    const float* bp3 = (const float*)d_in[7];
    const float* P0  = (const float*)d_in[8];
    const float* Wg0 = (const float*)d_in[9];
    const float* bg0 = (const float*)d_in[10];
    const float* Wg1 = (const float*)d_in[11];
    const float* bg1 = (const float*)d_in[12];
    // d_in[13], d_in[14] = Wg2/bg2: dead in reference
    const float* Wl1 = (const float*)d_in[15];
    const float* bl1 = (const float*)d_in[16];
    const float* Wl2 = (const float*)d_in[17];
    const float* bl2 = (const float*)d_in[18];
    float* out = (float*)d_out;

    char* wsb = (char*)d_ws;
    __hip_bfloat16* xb     = (__hip_bfloat16*)(wsb + XB_B);
    __hip_bfloat16* xj     = (__hip_bfloat16*)(wsb + XJ_B);
    __hip_bfloat16* hid    = (__hip_bfloat16*)(wsb + HID_B);
    __hip_bfloat16* h1     = (__hip_bfloat16*)(wsb + H1_B);
    __hip_bfloat16* xw     = (__hip_bfloat16*)(wsb + XW_B);
    __hip_bfloat16* h2     = (__hip_bfloat16*)(wsb + H2_B);
    __hip_bfloat16* lg     = (__hip_bfloat16*)(wsb + LG_B);
    __hip_bfloat16* pe     = (__hip_bfloat16*)(wsb + PE_B);
    int*            csr_row= (int*)(wsb + CSRR_B);
    float*          ew_csr = (float*)(wsb + EWC_B);
    int*            csr_col= (int*)(wsb + CSRW_B);   // overlays csr_w (dead until csrw_kernel)
    float*          csr_w  = (float*)(wsb + CSRW_B);
    int*            cnt    = (int*)(wsb + CNT_B);
    double*         S      = (double*)(wsb + S_B);
    int*            rowptr = (int*)(wsb + RP_B);
    int*            woff   = (int*)(wsb + WOFF_B);
    int*            incl   = (int*)(wsb + INCL_B);
    int*            bsum   = (int*)(wsb + BSUM_B);
    float*          st     = (float*)(wsb + ST_B);
    float*          dis    = (float*)(wsb + DIS_B);

    __hip_bfloat16* Wp1t = (__hip_bfloat16*)(wsb + WT_B + WP1T_O);
    __hip_bfloat16* Wg0t = (__hip_bfloat16*)(wsb + WT_B + WG0T_O);
    __hip_bfloat16* Wp2t = (__hip_bfloat16*)(wsb + WT_B + WP2T_O);
    __hip_bfloat16* Wp3t = (__hip_bfloat16*)(wsb + WT_B + WP3T_O);
    __hip_bfloat16* P0t  = (__hip_bfloat16*)(wsb + WT_B + P0T_O);
    __hip_bfloat16* Wg1t = (__hip_bfloat16*)(wsb + WT_B + WG1T_O);
    __hip_bfloat16* Wl1t = (__hip_bfloat16*)(wsb + WT_B + WL1T_O);
    __hip_bfloat16* Wl2t = (__hip_bfloat16*)(wsb + WT_B + WL2T_O);

    const int EB = (NEDGES + 255) / 256;            // 3125
    const int NB = (NNODES + 255) / 256;            // 196
    const int MT = (NNODES + 127) / 128;            // 391 row tiles
    const int BIGN = 1 << 30;

    hipMemsetAsync(wsb + CNT_B, 0, ZERO_BYTES, stream);

    // --- prep: weight transpose+cast, x cast ---
    WP wp;
    wp.w[0] = { Wp1, Wp1t, 512, 512, 0 };
    wp.w[1] = { Wg0, Wg0t, 512, 128, 0 };
    wp.w[2] = { Wp2, Wp2t, 512,  64, 0 };
    wp.w[3] = { Wp3, Wp3t,  64,  64, 0 };
    wp.w[4] = { P0,  P0t,   64,  64, 1 };   // relu(2*P)
    wp.w[5] = { Wg1, Wg1t, 128, 128, 0 };
    wp.w[6] = { Wl1, Wl1t, 256, 128, 0 };
    wp.w[7] = { Wl2, Wl2t, 128,  64, 0 };
    transpose_cast_all<<<dim3(1024, 8), 256, 0, stream>>>(wp);
    cast_x_kernel<<<12500, 256, 0, stream>>>(x, xb, (long)NNODES * IND);

    // --- CSR build (indices only; independent of ew) ---
    count_kernel<<<EB, 256, 0, stream>>>(ei, cnt);
    scan1_kernel<<<NB, 256, 0, stream>>>(cnt, incl, bsum);
    scan2_kernel<<<1, 256, 0, stream>>>(bsum, NB);
    scan3_kernel<<<NB, 256, 0, stream>>>(cnt, incl, bsum, rowptr, woff);
    scatter_idx_kernel<<<EB, 256, 0, stream>>>(ei, woff, csr_row, csr_col);

    // --- fused G1: [h1 | xw] = xb @ [Wp1 | Wg0]^T  (bf16 A, XCD-swizzled)
    gemm_mfma<128, 64><<<dim3(5, MT), 256, 0, stream>>>(
        xb, 512, Wp1t, 512, bp1, h1, 512, xw, 128, 512, NNODES, 512, 1, 1);

    // --- edge-weight MLP tail ---
    gemm_mfma<64, 32><<<dim3(1, MT), 256, 0, stream>>>(
        h1, 512, Wp2t, 512, bp2, h2, 64, nullptr, 0, BIGN, NNODES, 512, 1, 1);
    gemm_mfma<64, 32><<<dim3(1, MT), 256, 0, stream>>>(
        h2, 64, Wp3t, 64, bp3, lg, 64, nullptr, 0, BIGN, NNODES, 64, 0, 1);
    gemm_mfma<64, 32><<<dim3(1, MT), 256, 0, stream>>>(
        lg, 64, P0t, 64, nullptr, pe, 64, nullptr, 0, BIGN, NNODES, 64, 0, 1);

    // --- per-edge weights (8-lane cooperative) + stats ---
    edge_ew_gather<<<(NEDGES + 31) / 32, 256, 0, stream>>>(lg, pe, csr_row, csr_col, ew_csr);
    ew_stats_kernel<<<512, 256, 0, stream>>>(ew_csr, S);
    stats_kernel<<<1, 1, 0, stream>>>(S, st);
    norm_deg_kernel<<<NB, 256, 0, stream>>>(rowptr, ew_csr, st, dis);
    csrw_kernel<<<NB, 256, 0, stream>>>(rowptr, csr_row, ew_csr, dis, csr_w);

    // --- GCN layer 0 aggregation (xw from fused G1) ---
    agg_kernel<<<NNODES, HD, 0, stream>>>(xw, dis, rowptr, csr_row, csr_w, bg0, xj, 2 * HD);

    // --- GCN layer 1 ---
    gemm_mfma<64, 32><<<dim3(2, MT), 256, 0, stream>>>(
        xj, 2 * HD, Wg1t, 128, nullptr, xw, 128, nullptr, 0, BIGN, NNODES, 128, 0, 1);
    agg_kernel<<<NNODES, HD, 0, stream>>>(xw, dis, rowptr, csr_row, csr_w, bg1, xj + HD, 2 * HD);

    // --- JK head ---
    gemm_mfma<128, 64><<<dim3(1, MT), 256, 0, stream>>>(
        xj, 2 * HD, Wl1t, 256, bl1, hid, 128, nullptr, 0, BIGN, NNODES, 256, 1, 1);
    gemm_mfma<64, 32><<<dim3(1, MT), 256, 0, stream>>>(
        hid, 128, Wl2t, 128, bl2, out, 64, nullptr, 0, BIGN, NNODES, 128, 0, 0);
}

// Round 9
// 669.502 us; speedup vs baseline: 1.4257x; 1.0140x over previous
//
#include <hip/hip_runtime.h>
#include <hip/hip_bf16.h>
#include <cmath>

#define NNODES 50000
#define NEDGES 800000
#define IND    512
#define HD     128
#define CD     64

typedef __bf16 bf16x8 __attribute__((ext_vector_type(8)));
typedef float  f32x4  __attribute__((ext_vector_type(4)));
typedef const __attribute__((address_space(1))) unsigned int* gu32p;
typedef __attribute__((address_space(3))) unsigned int* lu32p;

// ---------------- workspace layout (byte offsets) ----------------
// xb (bf16 50000x512, 51.2MB) dead after G1 -> reused for xj + hid
static const size_t XB_B   = 0;           // bf16 50000x512
static const size_t XJ_B   = 0;           // bf16 50000x256 (after xb dead)
static const size_t HID_B  = 25600000;    // bf16 50000x128 (JK head, late)
static const size_t H1_B   = 51200000;    // bf16 50000x512
static const size_t XW_B   = 102400000;   // bf16 50000x128
static const size_t H2_B   = 115200000;   // bf16 50000x64
static const size_t LG_B   = 121600000;   // bf16 50000x64
static const size_t PE_B   = 128000000;   // bf16 50000x64
static const size_t WT_B   = 134400000;   // transposed bf16 weights + biases (~0.9MB)
static const size_t CSRR_B = 135300000;   // int 800000 (csr row index)
static const size_t EWC_B  = 138500000;   // fp32 800000 (ew in CSR order; normalized in place)
// csr_col overlays csr_w: csr_col written by scatter, last read by edge_ew_gather;
// csr_w first written by csrw_kernel which runs strictly AFTER edge_ew_gather.
static const size_t CSRW_B = 141700000;   // int csr_col -> then fp32 csr_w
static const size_t CNT_B  = 144900000;   // int 50000   (zero block start)
static const size_t S_B    = 145100000;   // 2 doubles
static const size_t ZERO_BYTES = 200016;  // cnt + S
static const size_t RP_B   = 145100016;   // int 50001
static const size_t WOFF_B = 145300020;   // int 50000
static const size_t INCL_B = 145500020;   // int 50000
static const size_t BSUM_B = 145700020;   // int 256
static const size_t ST_B   = 145701044;   // 2 floats
static const size_t DIS_B  = 145701052;   // fp32 50000
// total ~145.9 MB

// weight sub-offsets (bytes within WT_B). Wp1t then Wg0t CONTIGUOUS (G1 fused
// Bt [640,512]); Wp3t then W2t=(Wp3@P)t CONTIGUOUS (G3 fused Bt [128,64]).
static const size_t WP1T_O = 0;       // 512x512
static const size_t WG0T_O = 524288;  // 128x512
static const size_t WP2T_O = 655360;  // 64x512
static const size_t WP3T_O = 720896;  // 64x64
static const size_t W2T_O  = 729088;  // 64x64 (Wp3 @ relu(2*P0), transposed)
static const size_t WG1T_O = 737280;  // 128x128
static const size_t WL1T_O = 770048;  // 128x256
static const size_t WL2T_O = 835584;  // 64x128
static const size_t BG1_O  = 851968;  // fp32 640: [bp1 | zeros(128)]
static const size_t BG3_O  = 854528;  // fp32 128: [bp3 | bp3@P]

// ---------------- weight transpose+cast: dst[n*K+k] = cvt(src[k*N+n]) ------
struct WD { const float* s; __hip_bfloat16* d; int K; int N; };
struct WP { WD w[7]; };

__global__ __launch_bounds__(256) void transpose_cast_all(WP p)
{
    WD d = p.w[blockIdx.y];
    int i = blockIdx.x * 256 + threadIdx.x;
    if (i >= d.K * d.N) return;
    int k = i % d.K, n = i / d.K;
    d.d[i] = __float2bfloat16(d.s[(size_t)k * d.N + n]);
}

// ---------------- prep: W2t = (Wp3 @ relu(2*P0))^T, bias concats -----------
__global__ __launch_bounds__(256) void combine_p0(
    const float* __restrict__ Wp3, const float* __restrict__ bp3,
    const float* __restrict__ P0, const float* __restrict__ bp1,
    __hip_bfloat16* __restrict__ W2t, float* __restrict__ bias_g1,
    float* __restrict__ bias_g3)
{
    int b = blockIdx.x;
    if (b < 16) {
        int i = b * 256 + threadIdx.x;   // k = i>>6, n = i&63
        int k = i >> 6, n = i & 63;
        float s = 0.f;
        for (int j = 0; j < 64; j++)
            s += Wp3[k * 64 + j] * fmaxf(2.f * P0[j * 64 + n], 0.f);
        W2t[n * 64 + k] = __float2bfloat16(s);
    } else if (b == 16) {
        int n = threadIdx.x;
        if (n < 64) {
            float s = 0.f;
            for (int j = 0; j < 64; j++)
                s += bp3[j] * fmaxf(2.f * P0[j * 64 + n], 0.f);
            bias_g3[n] = bp3[n];
            bias_g3[64 + n] = s;
        }
    } else {
        int i = (b - 17) * 256 + threadIdx.x;   // 0..767
        if (i < 512) bias_g1[i] = bp1[i];
        else if (i < 640) bias_g1[i] = 0.f;
    }
}

// ---------------- cast x -> bf16 (8 elems/thread) --------------------------
__global__ __launch_bounds__(256) void cast_x_kernel(
    const float* __restrict__ x, __hip_bfloat16* __restrict__ xb, long n)
{
    long i = ((long)blockIdx.x * 256 + threadIdx.x) * 8;
    if (i >= n) return;
    float4 a = *(const float4*)(x + i);
    float4 b = *(const float4*)(x + i + 4);
    __hip_bfloat16 o[8] __attribute__((aligned(16)));
    o[0] = __float2bfloat16(a.x); o[1] = __float2bfloat16(a.y);
    o[2] = __float2bfloat16(a.z); o[3] = __float2bfloat16(a.w);
    o[4] = __float2bfloat16(b.x); o[5] = __float2bfloat16(b.y);
    o[6] = __float2bfloat16(b.z); o[7] = __float2bfloat16(b.w);
    *(int4*)(xb + i) = *(const int4*)o;
}

// ---------------- bf16 MFMA GEMM: C = act(A[M,K] @ Bt[N,K]^T + bias) -------
// BM=128, 4 waves, wave tile 64 x WN, BN = 2*WN. K%32==0, N%BN==0.
// m97-style staging: global_load_lds width=16, unpadded [rows][32] LDS tiles.
// Staging reads are NOT row-guarded (OOB rows land in adjacent ws regions and
// feed only unstored output rows). Blocks XCD-swizzled (NC col-tiles of a row
// strip share lin%8). splitN: cols >= splitN -> Cout2 (bf16, no relu); bias
// is applied to ALL cols (pad bias arrays with zeros where none wanted).
template<int BN, int WN>
__global__ __launch_bounds__(256) void gemm_mfma(
    const __hip_bfloat16* __restrict__ A, int lda,
    const __hip_bfloat16* __restrict__ Bt, int ldb,
    const float* __restrict__ bias,
    void* __restrict__ Cout, int ldc,
    void* __restrict__ Cout2, int ldc2, int splitN,
    int M, int K, int do_relu, int out_bf16)
{
    constexpr int BF = WN / 16;
    constexpr int BPASS = BN / 64;
    __shared__ __bf16 As[128 * 32];
    __shared__ __bf16 Bs[BN * 32];

    const int NC = gridDim.x, NR = gridDim.y;
    int g = blockIdx.y * NC + blockIdx.x;
    int per = NC * 8;
    int nfull = (NR >> 3) * per;
    int rowt, colt;
    if (g < nfull) {
        int grp = g / per, rem = g % per;
        rowt = grp * 8 + (rem & 7);
        colt = rem >> 3;
    } else {
        int rem = g - nfull;
        int tail = NR - (NR >> 3) * 8;
        rowt = (NR >> 3) * 8 + rem % tail;
        colt = rem / tail;
    }

    const int t = threadIdx.x;
    const int row0 = rowt * 128;
    const int col0 = colt * BN;

    const int wv   = t >> 6;
    const int lane = t & 63;
    const int quad = lane >> 4;
    const int l16  = lane & 15;
    const int wrow = (wv >> 1) * 64;
    const int wcol = (wv & 1) * WN;

    const int subrow = lane >> 2;          // 0..15
    const int subkg  = (lane & 3) * 8;     // 0,8,16,24

    f32x4 acc[4][BF] = {};

    for (int k0 = 0; k0 < K; k0 += 32) {
        // A tile: 128 rows x 32 halves. wave pass (p,wv) covers 16 rows.
        #pragma unroll
        for (int p = 0; p < 2; p++) {
            int rowA = (p * 4 + wv) * 16 + subrow;
            const __hip_bfloat16* gp = A + (size_t)(row0 + rowA) * lda + k0 + subkg;
            __builtin_amdgcn_global_load_lds((gu32p)(const void*)gp,
                (lu32p)(void*)&As[(p * 4 + wv) * 512], 16, 0, 0);
        }
        #pragma unroll
        for (int p = 0; p < BPASS; p++) {
            int rowB = (p * 4 + wv) * 16 + subrow;
            const __hip_bfloat16* gp = Bt + (size_t)(col0 + rowB) * ldb + k0 + subkg;
            __builtin_amdgcn_global_load_lds((gu32p)(const void*)gp,
                (lu32p)(void*)&Bs[(p * 4 + wv) * 512], 16, 0, 0);
        }
        __syncthreads();

        bf16x8 af[4], bfr[BF];
        #pragma unroll
        for (int i = 0; i < 4; i++)
            af[i] = *(const bf16x8*)&As[(wrow + i * 16 + l16) * 32 + quad * 8];
        #pragma unroll
        for (int j = 0; j < BF; j++)
            bfr[j] = *(const bf16x8*)&Bs[(wcol + j * 16 + l16) * 32 + quad * 8];
        #pragma unroll
        for (int i = 0; i < 4; i++)
            #pragma unroll
            for (int j = 0; j < BF; j++)
                acc[i][j] = __builtin_amdgcn_mfma_f32_16x16x32_bf16(af[i], bfr[j], acc[i][j], 0, 0, 0);
        __syncthreads();
    }

    #pragma unroll
    for (int i = 0; i < 4; i++) {
        #pragma unroll
        for (int j = 0; j < BF; j++) {
            int n = col0 + wcol + j * 16 + l16;
            bool second = (n >= splitN);
            float bv = bias ? bias[n] : 0.f;
            #pragma unroll
            for (int reg = 0; reg < 4; reg++) {
                int m = row0 + wrow + i * 16 + quad * 4 + reg;
                if (m >= M) continue;
                float v = acc[i][j][reg] + bv;
                if (do_relu && !second) v = fmaxf(v, 0.f);
                if (second)
                    ((__hip_bfloat16*)Cout2)[(size_t)m * ldc2 + (n - splitN)] = __float2bfloat16(v);
                else if (out_bf16)
                    ((__hip_bfloat16*)Cout)[(size_t)m * ldc + n] = __float2bfloat16(v);
                else
                    ((float*)Cout)[(size_t)m * ldc + n] = v;
            }
        }
    }
}

// ---------------- CSR build (indices only) ---------------------------------
__global__ __launch_bounds__(256) void count_kernel(
    const int* __restrict__ ei, int* __restrict__ cnt)
{
    int e = blockIdx.x * 256 + threadIdx.x;
    if (e >= NEDGES) return;
    atomicAdd(&cnt[ei[NEDGES + e]], 1);
}

__global__ __launch_bounds__(256) void scan1_kernel(
    const int* __restrict__ cnt, int* __restrict__ incl, int* __restrict__ bsum)
{
    __shared__ int s[256];
    int t = threadIdx.x;
    int i = blockIdx.x * 256 + t;
    int v = (i < NNODES) ? cnt[i] : 0;
    s[t] = v;
    __syncthreads();
    for (int off = 1; off < 256; off <<= 1) {
        int u = (t >= off) ? s[t - off] : 0;
        __syncthreads();
        s[t] += u;
        __syncthreads();
    }
    if (i < NNODES) incl[i] = s[t];
    if (t == 255) bsum[blockIdx.x] = s[255];
}

__global__ __launch_bounds__(256) void scan2_kernel(int* __restrict__ bsum, int nb)
{
    __shared__ int s[256];
    int t = threadIdx.x;
    int v = (t < nb) ? bsum[t] : 0;
    s[t] = v;
    __syncthreads();
    for (int off = 1; off < 256; off <<= 1) {
        int u = (t >= off) ? s[t - off] : 0;
        __syncthreads();
        s[t] += u;
        __syncthreads();
    }
    if (t < nb) bsum[t] = s[t] - v;   // exclusive block offset
}

__global__ __launch_bounds__(256) void scan3_kernel(
    const int* __restrict__ cnt, const int* __restrict__ incl,
    const int* __restrict__ bsum, int* __restrict__ rowptr, int* __restrict__ woff)
{
    int i = blockIdx.x * 256 + threadIdx.x;
    if (i >= NNODES) return;
    int off = bsum[blockIdx.x];
    int r = incl[i] - cnt[i] + off;
    rowptr[i] = r;
    woff[i] = r;
    if (i == NNODES - 1) rowptr[NNODES] = incl[i] + off;
}

__global__ __launch_bounds__(256) void scatter_idx_kernel(
    const int* __restrict__ ei, int* __restrict__ woff,
    int* __restrict__ csr_row, int* __restrict__ csr_col)
{
    int e = blockIdx.x * 256 + threadIdx.x;
    if (e >= NEDGES) return;
    int r = ei[e];
    int c = ei[NEDGES + e];
    int p = atomicAdd(&woff[c], 1);
    csr_row[p] = r;
    csr_col[p] = c;
}

// ---------------- edge weight: 8 lanes cooperate per edge ------------------
__global__ __launch_bounds__(256) void edge_ew_gather(
    const __hip_bfloat16* __restrict__ lg, const __hip_bfloat16* __restrict__ pe,
    const int* __restrict__ csr_row, const int* __restrict__ csr_col,
    float* __restrict__ ew_csr)
{
    const int tid = threadIdx.x;
    const int sub = tid & 7;
    const int e = blockIdx.x * 32 + (tid >> 3);
    if (e >= NEDGES) return;
    int r = csr_row[e];
    int c = csr_col[e];
    bf16x8 a = *(const bf16x8*)(lg + (size_t)r * CD + sub * 8);
    bf16x8 b = *(const bf16x8*)(pe + (size_t)c * CD + sub * 8);
    float acc = 0.f;
    #pragma unroll
    for (int u = 0; u < 8; u++)
        acc += (float)a[u] * (float)b[u];
    acc += __shfl_xor(acc, 1);
    acc += __shfl_xor(acc, 2);
    acc += __shfl_xor(acc, 4);
    if (sub == 0) ew_csr[e] = acc;
}

// grid-stride stats over the dense ew array (sequential read, ~3.2MB)
__global__ __launch_bounds__(256) void ew_stats_kernel(
    const float* __restrict__ ew, double* __restrict__ S)
{
    const int tid = threadIdx.x;
    double s1 = 0.0, s2 = 0.0;
    for (int i = blockIdx.x * 256 + tid; i < NEDGES; i += gridDim.x * 256) {
        float v = ew[i];
        s1 += v; s2 += (double)v * (double)v;
    }
    __shared__ double sh1[256], sh2[256];
    sh1[tid] = s1; sh2[tid] = s2;
    __syncthreads();
    for (int s = 128; s > 0; s >>= 1) {
        if (tid < s) { sh1[tid] += sh1[tid + s]; sh2[tid] += sh2[tid + s]; }
        __syncthreads();
    }
    if (tid == 0) {
        atomicAdd(&S[0], sh1[0]);
        atomicAdd(&S[1], sh2[0]);
    }
}

__global__ void stats_kernel(const double* __restrict__ S, float* __restrict__ st)
{
    double E = (double)NEDGES;
    double mean = S[0] / E;
    double var = (S[1] - S[0] * S[0] / E) / (E - 1.0);
    st[0] = (float)mean;
    st[1] = (float)sqrt(1e-4 / var);
}

// per node: normalize segment in place, deg = segment sum, dis = rsqrt(deg+1)
__global__ __launch_bounds__(256) void norm_deg_kernel(
    const int* __restrict__ rowptr, float* __restrict__ ew_csr,
    const float* __restrict__ st, float* __restrict__ dis)
{
    int n = blockIdx.x * 256 + threadIdx.x;
    if (n >= NNODES) return;
    float mean = st[0], alpha = st[1];
    int s = rowptr[n], e = rowptr[n + 1];
    float sum = 0.f;
    for (int j = s; j < e; j++) {
        float w = (ew_csr[j] - mean) * alpha + 1.0f;
        ew_csr[j] = w;
        sum += w;
    }
    float d = sum + 1.0f;                       // self-loop weight 1
    dis[n] = (d > 0.f) ? rsqrtf(d) : 0.f;
}

// per node: csr_w[j] = dis[row]*w*dis[n]  (csr_w overlays the dead csr_col)
__global__ __launch_bounds__(256) void csrw_kernel(
    const int* __restrict__ rowptr, const int* __restrict__ csr_row,
    const float* __restrict__ ew_csr, const float* __restrict__ dis,
    float* __restrict__ csr_w)
{
    int n = blockIdx.x * 256 + threadIdx.x;
    if (n >= NNODES) return;
    float dn = dis[n];
    int s = rowptr[n], e = rowptr[n + 1];
    for (int j = s; j < e; j++)
        csr_w[j] = dis[csr_row[j]] * ew_csr[j] * dn;
}

// ---------------- weighted aggregation (bf16 in, bf16 out, fp32 acc) ------
__global__ __launch_bounds__(128) void agg_kernel(
    const __hip_bfloat16* __restrict__ xw, const float* __restrict__ dis,
    const int* __restrict__ rowptr, const int* __restrict__ csr_row,
    const float* __restrict__ csr_w, const float* __restrict__ bias,
    __hip_bfloat16* __restrict__ out, int ldo)
{
    int n = blockIdx.x;
    int f = threadIdx.x;
    float dn = dis[n];
    float acc = dn * dn * __bfloat162float(xw[(size_t)n * HD + f]);
    int s = rowptr[n], e = rowptr[n + 1];
    for (int j = s; j < e; j++) {
        int r = csr_row[j];
        float w = csr_w[j];
        acc += w * __bfloat162float(xw[(size_t)r * HD + f]);
    }
    out[(size_t)n * ldo + f] = __float2bfloat16(fmaxf(acc + bias[f], 0.f));
}

// ---------------- launch --------------------------------------------------
extern "C" void kernel_launch(void* const* d_in, const int* in_sizes, int n_in,
                              void* d_out, int out_size, void* d_ws, size_t ws_size,
                              hipStream_t stream)
{
    const float* x   = (const float*)d_in[0];
    const int*   ei  = (const int*)d_in[1];
    const float* Wp1 = (const float*)d_in[2];
    const float* bp1 = (const float*)d_in[3];
    const float* Wp2 = (const float*)d_in[4];
    const float* bp2 = (const float*)d_in[5];
    const float* Wp3 = (const float*)d_in[6];
    const float* bp3 = (const float*)d_in[7];
    const float* P0  = (const float*)d_in[8];
    const float* Wg0 = (const float*)d_in[9];
    const float* bg0 = (const float*)d_in[10];
    const float* Wg1 = (const float*)d_in[11];
    const float* bg1 = (const float*)d_in[12];
    // d_in[13], d_in[14] = Wg2/bg2: dead in reference
    const float* Wl1 = (const float*)d_in[15];
    const float* bl1 = (const float*)d_in[16];
    const float* Wl2 = (const float*)d_in[17];
    const float* bl2 = (const float*)d_in[18];
    float* out = (float*)d_out;

    char* wsb = (char*)d_ws;
    __hip_bfloat16* xb     = (__hip_bfloat16*)(wsb + XB_B);
    __hip_bfloat16* xj     = (__hip_bfloat16*)(wsb + XJ_B);
    __hip_bfloat16* hid    = (__hip_bfloat16*)(wsb + HID_B);
    __hip_bfloat16* h1     = (__hip_bfloat16*)(wsb + H1_B);
    __hip_bfloat16* xw     = (__hip_bfloat16*)(wsb + XW_B);
    __hip_bfloat16* h2     = (__hip_bfloat16*)(wsb + H2_B);
    __hip_bfloat16* lg     = (__hip_bfloat16*)(wsb + LG_B);
    __hip_bfloat16* pe     = (__hip_bfloat16*)(wsb + PE_B);
    int*            csr_row= (int*)(wsb + CSRR_B);
    float*          ew_csr = (float*)(wsb + EWC_B);
    int*            csr_col= (int*)(wsb + CSRW_B);   // overlays csr_w (dead until csrw_kernel)
    float*          csr_w  = (float*)(wsb + CSRW_B);
    int*            cnt    = (int*)(wsb + CNT_B);
    double*         S      = (double*)(wsb + S_B);
    int*            rowptr = (int*)(wsb + RP_B);
    int*            woff   = (int*)(wsb + WOFF_B);
    int*            incl   = (int*)(wsb + INCL_B);
    int*            bsum   = (int*)(wsb + BSUM_B);
    float*          st     = (float*)(wsb + ST_B);
    float*          dis    = (float*)(wsb + DIS_B);

    __hip_bfloat16* Wp1t = (__hip_bfloat16*)(wsb + WT_B + WP1T_O);
    __hip_bfloat16* Wg0t = (__hip_bfloat16*)(wsb + WT_B + WG0T_O);
    __hip_bfloat16* Wp2t = (__hip_bfloat16*)(wsb + WT_B + WP2T_O);
    __hip_bfloat16* Wp3t = (__hip_bfloat16*)(wsb + WT_B + WP3T_O);
    __hip_bfloat16* W2t  = (__hip_bfloat16*)(wsb + WT_B + W2T_O);
    __hip_bfloat16* Wg1t = (__hip_bfloat16*)(wsb + WT_B + WG1T_O);
    __hip_bfloat16* Wl1t = (__hip_bfloat16*)(wsb + WT_B + WL1T_O);
    __hip_bfloat16* Wl2t = (__hip_bfloat16*)(wsb + WT_B + WL2T_O);
    float*          bias_g1 = (float*)(wsb + WT_B + BG1_O);
    float*          bias_g3 = (float*)(wsb + WT_B + BG3_O);

    const int EB = (NEDGES + 255) / 256;            // 3125
    const int NB = (NNODES + 255) / 256;            // 196
    const int MT = (NNODES + 127) / 128;            // 391 row tiles
    const int BIGN = 1 << 30;

    hipMemsetAsync(wsb + CNT_B, 0, ZERO_BYTES, stream);

    // --- prep: weight transpose+cast, fused Wp3@P fold, x cast ---
    WP wp;
    wp.w[0] = { Wp1, Wp1t, 512, 512 };
    wp.w[1] = { Wg0, Wg0t, 512, 128 };
    wp.w[2] = { Wp2, Wp2t, 512,  64 };
    wp.w[3] = { Wp3, Wp3t,  64,  64 };
    wp.w[4] = { Wg1, Wg1t, 128, 128 };
    wp.w[5] = { Wl1, Wl1t, 256, 128 };
    wp.w[6] = { Wl2, Wl2t, 128,  64 };
    transpose_cast_all<<<dim3(1024, 7), 256, 0, stream>>>(wp);
    combine_p0<<<20, 256, 0, stream>>>(Wp3, bp3, P0, bp1, W2t, bias_g1, bias_g3);
    cast_x_kernel<<<12500, 256, 0, stream>>>(x, xb, (long)NNODES * IND);

    // --- CSR build (indices only; independent of ew) ---
    count_kernel<<<EB, 256, 0, stream>>>(ei, cnt);
    scan1_kernel<<<NB, 256, 0, stream>>>(cnt, incl, bsum);
    scan2_kernel<<<1, 256, 0, stream>>>(bsum, NB);
    scan3_kernel<<<NB, 256, 0, stream>>>(cnt, incl, bsum, rowptr, woff);
    scatter_idx_kernel<<<EB, 256, 0, stream>>>(ei, woff, csr_row, csr_col);

    // --- fused G1: [h1 | xw] = xb @ [Wp1 | Wg0]^T ---
    // cols 0..511: relu(.+bp1) -> h1 ; cols 512..639: raw (+0 bias) -> xw
    gemm_mfma<128, 64><<<dim3(5, MT), 256, 0, stream>>>(
        xb, 512, Wp1t, 512, bias_g1, h1, 512, xw, 128, 512, NNODES, 512, 1, 1);

    // --- G2: h2 = relu(h1 @ Wp2 + bp2) ---
    gemm_mfma<64, 32><<<dim3(1, MT), 256, 0, stream>>>(
        h1, 512, Wp2t, 512, bp2, h2, 64, nullptr, 0, BIGN, NNODES, 512, 1, 1);

    // --- fused G3: [lg | pe] = h2 @ [Wp3 | Wp3@P]^T + [bp3 | bp3@P] ---
    gemm_mfma<128, 64><<<dim3(1, MT), 256, 0, stream>>>(
        h2, 64, Wp3t, 64, bias_g3, lg, 64, pe, 64, 64, NNODES, 64, 0, 1);

    // --- per-edge weights (8-lane cooperative) + stats ---
    edge_ew_gather<<<(NEDGES + 31) / 32, 256, 0, stream>>>(lg, pe, csr_row, csr_col, ew_csr);
    ew_stats_kernel<<<512, 256, 0, stream>>>(ew_csr, S);
    stats_kernel<<<1, 1, 0, stream>>>(S, st);
    norm_deg_kernel<<<NB, 256, 0, stream>>>(rowptr, ew_csr, st, dis);
    csrw_kernel<<<NB, 256, 0, stream>>>(rowptr, csr_row, ew_csr, dis, csr_w);

    // --- GCN layer 0 aggregation (xw from fused G1) ---
    agg_kernel<<<NNODES, HD, 0, stream>>>(xw, dis, rowptr, csr_row, csr_w, bg0, xj, 2 * HD);

    // --- GCN layer 1 ---
    gemm_mfma<64, 32><<<dim3(2, MT), 256, 0, stream>>>(
        xj, 2 * HD, Wg1t, 128, nullptr, xw, 128, nullptr, 0, BIGN, NNODES, 128, 0, 1);
    agg_kernel<<<NNODES, HD, 0, stream>>>(xw, dis, rowptr, csr_row, csr_w, bg1, xj + HD, 2 * HD);

    // --- JK head ---
    gemm_mfma<128, 64><<<dim3(1, MT), 256, 0, stream>>>(
        xj, 2 * HD, Wl1t, 256, bl1, hid, 128, nullptr, 0, BIGN, NNODES, 256, 1, 1);
    gemm_mfma<64, 32><<<dim3(1, MT), 256, 0, stream>>>(
        hid, 128, Wl2t, 128, bl2, out, 64, nullptr, 0, BIGN, NNODES, 128, 0, 0);
}

// Round 10
// 576.609 us; speedup vs baseline: 1.6553x; 1.1611x over previous
//
#include <hip/hip_runtime.h>
#include <hip/hip_bf16.h>
#include <cmath>
#include <cstring>

#define NNODES 50000
#define NEDGES 800000
#define IND    512
#define HD     128
#define CD     64

typedef __bf16 bf16x8 __attribute__((ext_vector_type(8)));
typedef float  f32x4  __attribute__((ext_vector_type(4)));
typedef const __attribute__((address_space(1))) unsigned int* gu32p;
typedef __attribute__((address_space(3))) unsigned int* lu32p;

// ---------------- workspace layout (byte offsets) ----------------
// xb (bf16 50000x512, 51.2MB) dead after G1 -> reused for xj + hid
static const size_t XB_B   = 0;           // bf16 50000x512
static const size_t XJ_B   = 0;           // bf16 50000x256 (after xb dead)
static const size_t HID_B  = 25600000;    // bf16 50000x128 (JK head, late)
static const size_t H1_B   = 51200000;    // bf16 50000x512
static const size_t XW_B   = 102400000;   // bf16 50000x128
static const size_t H2_B   = 115200000;   // bf16 50000x64
static const size_t LG_B   = 121600000;   // bf16 50000x64
static const size_t PE_B   = 128000000;   // bf16 50000x64
static const size_t WT_B   = 134400000;   // transposed bf16 weights + biases (~0.9MB)
static const size_t CSRR_B = 135300000;   // int 800000 (csr row index)
static const size_t EWC_B  = 138500000;   // fp32 800000 (ew in CSR order; normalized in place)
// csr_col overlays csr_w: csr_col written by scatter, last read by edge_ew_gather;
// csr_w first written by csrw_kernel which runs strictly AFTER edge_ew_gather.
static const size_t CSRW_B = 141700000;   // int csr_col -> then fp32 csr_w
static const size_t CNT_B  = 144900000;   // int 50000   (zero block start)
static const size_t S_B    = 145100000;   // 2 doubles
static const size_t ZERO_BYTES = 200016;  // cnt + S
static const size_t RP_B   = 145100016;   // int 50001
static const size_t WOFF_B = 145300020;   // int 50000
static const size_t INCL_B = 145500020;   // int 50000
static const size_t BSUM_B = 145700020;   // int 256
static const size_t ST_B   = 145701044;   // 2 floats
static const size_t DIS_B  = 145701052;   // fp32 50000
// total ~145.9 MB

// weight sub-offsets (bytes within WT_B). Wp1t then Wg0t CONTIGUOUS (G1 fused
// Bt [640,512]); Wp3t then W2t=(Wp3@P)t CONTIGUOUS (G3 fused Bt [128,64]).
static const size_t WP1T_O = 0;       // 512x512
static const size_t WG0T_O = 524288;  // 128x512
static const size_t WP2T_O = 655360;  // 64x512
static const size_t WP3T_O = 720896;  // 64x64
static const size_t W2T_O  = 729088;  // 64x64 (Wp3 @ relu(2*P0), transposed)
static const size_t WG1T_O = 737280;  // 128x128
static const size_t WL1T_O = 770048;  // 128x256
static const size_t WL2T_O = 835584;  // 64x128
static const size_t BG1_O  = 851968;  // fp32 640: [bp1 | zeros(128)]
static const size_t BG3_O  = 854528;  // fp32 128: [bp3 | bp3@P]

// ---------------- weight transpose+cast: dst[n*K+k] = cvt(src[k*N+n]) ------
struct WD { const float* s; __hip_bfloat16* d; int K; int N; };
struct WP { WD w[7]; };

__global__ __launch_bounds__(256) void transpose_cast_all(WP p)
{
    WD d = p.w[blockIdx.y];
    int i = blockIdx.x * 256 + threadIdx.x;
    if (i >= d.K * d.N) return;
    int k = i % d.K, n = i / d.K;
    d.d[i] = __float2bfloat16(d.s[(size_t)k * d.N + n]);
}

// ---------------- prep: W2t = (Wp3 @ relu(2*P0))^T, bias concats -----------
__global__ __launch_bounds__(256) void combine_p0(
    const float* __restrict__ Wp3, const float* __restrict__ bp3,
    const float* __restrict__ P0, const float* __restrict__ bp1,
    __hip_bfloat16* __restrict__ W2t, float* __restrict__ bias_g1,
    float* __restrict__ bias_g3)
{
    int b = blockIdx.x;
    if (b < 16) {
        int i = b * 256 + threadIdx.x;   // k = i>>6, n = i&63
        int k = i >> 6, n = i & 63;
        float s = 0.f;
        for (int j = 0; j < 64; j++)
            s += Wp3[k * 64 + j] * fmaxf(2.f * P0[j * 64 + n], 0.f);
        W2t[n * 64 + k] = __float2bfloat16(s);
    } else if (b == 16) {
        int n = threadIdx.x;
        if (n < 64) {
            float s = 0.f;
            for (int j = 0; j < 64; j++)
                s += bp3[j] * fmaxf(2.f * P0[j * 64 + n], 0.f);
            bias_g3[n] = bp3[n];
            bias_g3[64 + n] = s;
        }
    } else {
        int i = (b - 17) * 256 + threadIdx.x;   // 0..767
        if (i < 512) bias_g1[i] = bp1[i];
        else if (i < 640) bias_g1[i] = 0.f;
    }
}

// ---------------- cast x -> bf16 (8 elems/thread) --------------------------
__global__ __launch_bounds__(256) void cast_x_kernel(
    const float* __restrict__ x, __hip_bfloat16* __restrict__ xb, long n)
{
    long i = ((long)blockIdx.x * 256 + threadIdx.x) * 8;
    if (i >= n) return;
    float4 a = *(const float4*)(x + i);
    float4 b = *(const float4*)(x + i + 4);
    __hip_bfloat16 o[8] __attribute__((aligned(16)));
    o[0] = __float2bfloat16(a.x); o[1] = __float2bfloat16(a.y);
    o[2] = __float2bfloat16(a.z); o[3] = __float2bfloat16(a.w);
    o[4] = __float2bfloat16(b.x); o[5] = __float2bfloat16(b.y);
    o[6] = __float2bfloat16(b.z); o[7] = __float2bfloat16(b.w);
    *(int4*)(xb + i) = *(const int4*)o;
}

// ---------------- bf16 MFMA GEMM: C = act(A[M,K] @ Bt[N,K]^T + bias) -------
// BM=128, 4 waves, wave tile 64 x WN, BN = 2*WN. K%32==0, N%BN==0.
// m97-style staging: global_load_lds width=16, unpadded [rows][32] LDS tiles.
// Staging reads are NOT row-guarded (OOB rows land in adjacent ws regions and
// feed only unstored output rows). Blocks XCD-swizzled (NC col-tiles of a row
// strip share lin%8). splitN: cols >= splitN -> Cout2 (bf16, no relu); bias
// is applied to ALL cols (pad bias arrays with zeros where none wanted).
template<int BN, int WN>
__global__ __launch_bounds__(256) void gemm_mfma(
    const __hip_bfloat16* __restrict__ A, int lda,
    const __hip_bfloat16* __restrict__ Bt, int ldb,
    const float* __restrict__ bias,
    void* __restrict__ Cout, int ldc,
    void* __restrict__ Cout2, int ldc2, int splitN,
    int M, int K, int do_relu, int out_bf16)
{
    constexpr int BF = WN / 16;
    constexpr int BPASS = BN / 64;
    __shared__ __bf16 As[128 * 32];
    __shared__ __bf16 Bs[BN * 32];

    const int NC = gridDim.x, NR = gridDim.y;
    int g = blockIdx.y * NC + blockIdx.x;
    int per = NC * 8;
    int nfull = (NR >> 3) * per;
    int rowt, colt;
    if (g < nfull) {
        int grp = g / per, rem = g % per;
        rowt = grp * 8 + (rem & 7);
        colt = rem >> 3;
    } else {
        int rem = g - nfull;
        int tail = NR - (NR >> 3) * 8;
        rowt = (NR >> 3) * 8 + rem % tail;
        colt = rem / tail;
    }

    const int t = threadIdx.x;
    const int row0 = rowt * 128;
    const int col0 = colt * BN;

    const int wv   = t >> 6;
    const int lane = t & 63;
    const int quad = lane >> 4;
    const int l16  = lane & 15;
    const int wrow = (wv >> 1) * 64;
    const int wcol = (wv & 1) * WN;

    const int subrow = lane >> 2;          // 0..15
    const int subkg  = (lane & 3) * 8;     // 0,8,16,24

    f32x4 acc[4][BF] = {};

    for (int k0 = 0; k0 < K; k0 += 32) {
        #pragma unroll
        for (int p = 0; p < 2; p++) {
            int rowA = (p * 4 + wv) * 16 + subrow;
            const __hip_bfloat16* gp = A + (size_t)(row0 + rowA) * lda + k0 + subkg;
            __builtin_amdgcn_global_load_lds((gu32p)(const void*)gp,
                (lu32p)(void*)&As[(p * 4 + wv) * 512], 16, 0, 0);
        }
        #pragma unroll
        for (int p = 0; p < BPASS; p++) {
            int rowB = (p * 4 + wv) * 16 + subrow;
            const __hip_bfloat16* gp = Bt + (size_t)(col0 + rowB) * ldb + k0 + subkg;
            __builtin_amdgcn_global_load_lds((gu32p)(const void*)gp,
                (lu32p)(void*)&Bs[(p * 4 + wv) * 512], 16, 0, 0);
        }
        __syncthreads();

        bf16x8 af[4], bfr[BF];
        #pragma unroll
        for (int i = 0; i < 4; i++)
            af[i] = *(const bf16x8*)&As[(wrow + i * 16 + l16) * 32 + quad * 8];
        #pragma unroll
        for (int j = 0; j < BF; j++)
            bfr[j] = *(const bf16x8*)&Bs[(wcol + j * 16 + l16) * 32 + quad * 8];
        #pragma unroll
        for (int i = 0; i < 4; i++)
            #pragma unroll
            for (int j = 0; j < BF; j++)
                acc[i][j] = __builtin_amdgcn_mfma_f32_16x16x32_bf16(af[i], bfr[j], acc[i][j], 0, 0, 0);
        __syncthreads();
    }

    #pragma unroll
    for (int i = 0; i < 4; i++) {
        #pragma unroll
        for (int j = 0; j < BF; j++) {
            int n = col0 + wcol + j * 16 + l16;
            bool second = (n >= splitN);
            float bv = bias ? bias[n] : 0.f;
            #pragma unroll
            for (int reg = 0; reg < 4; reg++) {
                int m = row0 + wrow + i * 16 + quad * 4 + reg;
                if (m >= M) continue;
                float v = acc[i][j][reg] + bv;
                if (do_relu && !second) v = fmaxf(v, 0.f);
                if (second)
                    ((__hip_bfloat16*)Cout2)[(size_t)m * ldc2 + (n - splitN)] = __float2bfloat16(v);
                else if (out_bf16)
                    ((__hip_bfloat16*)Cout)[(size_t)m * ldc + n] = __float2bfloat16(v);
                else
                    ((float*)Cout)[(size_t)m * ldc + n] = v;
            }
        }
    }
}

// ---------------- CSR build (indices only) ---------------------------------
__global__ __launch_bounds__(256) void count_kernel(
    const int* __restrict__ ei, int* __restrict__ cnt)
{
    int e = blockIdx.x * 256 + threadIdx.x;
    if (e >= NEDGES) return;
    atomicAdd(&cnt[ei[NEDGES + e]], 1);
}

__global__ __launch_bounds__(256) void scan1_kernel(
    const int* __restrict__ cnt, int* __restrict__ incl, int* __restrict__ bsum)
{
    __shared__ int s[256];
    int t = threadIdx.x;
    int i = blockIdx.x * 256 + t;
    int v = (i < NNODES) ? cnt[i] : 0;
    s[t] = v;
    __syncthreads();
    for (int off = 1; off < 256; off <<= 1) {
        int u = (t >= off) ? s[t - off] : 0;
        __syncthreads();
        s[t] += u;
        __syncthreads();
    }
    if (i < NNODES) incl[i] = s[t];
    if (t == 255) bsum[blockIdx.x] = s[255];
}

__global__ __launch_bounds__(256) void scan2_kernel(int* __restrict__ bsum, int nb)
{
    __shared__ int s[256];
    int t = threadIdx.x;
    int v = (t < nb) ? bsum[t] : 0;
    s[t] = v;
    __syncthreads();
    for (int off = 1; off < 256; off <<= 1) {
        int u = (t >= off) ? s[t - off] : 0;
        __syncthreads();
        s[t] += u;
        __syncthreads();
    }
    if (t < nb) bsum[t] = s[t] - v;   // exclusive block offset
}

__global__ __launch_bounds__(256) void scan3_kernel(
    const int* __restrict__ cnt, const int* __restrict__ incl,
    const int* __restrict__ bsum, int* __restrict__ rowptr, int* __restrict__ woff)
{
    int i = blockIdx.x * 256 + threadIdx.x;
    if (i >= NNODES) return;
    int off = bsum[blockIdx.x];
    int r = incl[i] - cnt[i] + off;
    rowptr[i] = r;
    woff[i] = r;
    if (i == NNODES - 1) rowptr[NNODES] = incl[i] + off;
}

__global__ __launch_bounds__(256) void scatter_idx_kernel(
    const int* __restrict__ ei, int* __restrict__ woff,
    int* __restrict__ csr_row, int* __restrict__ csr_col)
{
    int e = blockIdx.x * 256 + threadIdx.x;
    if (e >= NEDGES) return;
    int r = ei[e];
    int c = ei[NEDGES + e];
    int p = atomicAdd(&woff[c], 1);
    csr_row[p] = r;
    csr_col[p] = c;
}

// ---------------- edge weight: 8 lanes cooperate per edge ------------------
__global__ __launch_bounds__(256) void edge_ew_gather(
    const __hip_bfloat16* __restrict__ lg, const __hip_bfloat16* __restrict__ pe,
    const int* __restrict__ csr_row, const int* __restrict__ csr_col,
    float* __restrict__ ew_csr)
{
    const int tid = threadIdx.x;
    const int sub = tid & 7;
    const int e = blockIdx.x * 32 + (tid >> 3);
    if (e >= NEDGES) return;
    int r = csr_row[e];
    int c = csr_col[e];
    bf16x8 a = *(const bf16x8*)(lg + (size_t)r * CD + sub * 8);
    bf16x8 b = *(const bf16x8*)(pe + (size_t)c * CD + sub * 8);
    float acc = 0.f;
    #pragma unroll
    for (int u = 0; u < 8; u++)
        acc += (float)a[u] * (float)b[u];
    acc += __shfl_xor(acc, 1);
    acc += __shfl_xor(acc, 2);
    acc += __shfl_xor(acc, 4);
    if (sub == 0) ew_csr[e] = acc;
}

// grid-stride stats over the dense ew array (sequential read, ~3.2MB)
__global__ __launch_bounds__(256) void ew_stats_kernel(
    const float* __restrict__ ew, double* __restrict__ S)
{
    const int tid = threadIdx.x;
    double s1 = 0.0, s2 = 0.0;
    for (int i = blockIdx.x * 256 + tid; i < NEDGES; i += gridDim.x * 256) {
        float v = ew[i];
        s1 += v; s2 += (double)v * (double)v;
    }
    __shared__ double sh1[256], sh2[256];
    sh1[tid] = s1; sh2[tid] = s2;
    __syncthreads();
    for (int s = 128; s > 0; s >>= 1) {
        if (tid < s) { sh1[tid] += sh1[tid + s]; sh2[tid] += sh2[tid + s]; }
        __syncthreads();
    }
    if (tid == 0) {
        atomicAdd(&S[0], sh1[0]);
        atomicAdd(&S[1], sh2[0]);
    }
}

__global__ void stats_kernel(const double* __restrict__ S, float* __restrict__ st)
{
    double E = (double)NEDGES;
    double mean = S[0] / E;
    double var = (S[1] - S[0] * S[0] / E) / (E - 1.0);
    st[0] = (float)mean;
    st[1] = (float)sqrt(1e-4 / var);
}

// per node: normalize segment in place, deg = segment sum, dis = rsqrt(deg+1)
__global__ __launch_bounds__(256) void norm_deg_kernel(
    const int* __restrict__ rowptr, float* __restrict__ ew_csr,
    const float* __restrict__ st, float* __restrict__ dis)
{
    int n = blockIdx.x * 256 + threadIdx.x;
    if (n >= NNODES) return;
    float mean = st[0], alpha = st[1];
    int s = rowptr[n], e = rowptr[n + 1];
    float sum = 0.f;
    for (int j = s; j < e; j++) {
        float w = (ew_csr[j] - mean) * alpha + 1.0f;
        ew_csr[j] = w;
        sum += w;
    }
    float d = sum + 1.0f;                       // self-loop weight 1
    dis[n] = (d > 0.f) ? rsqrtf(d) : 0.f;
}

// per node: csr_w[j] = dis[row]*w*dis[n]  (csr_w overlays the dead csr_col)
__global__ __launch_bounds__(256) void csrw_kernel(
    const int* __restrict__ rowptr, const int* __restrict__ csr_row,
    const float* __restrict__ ew_csr, const float* __restrict__ dis,
    float* __restrict__ csr_w)
{
    int n = blockIdx.x * 256 + threadIdx.x;
    if (n >= NNODES) return;
    float dn = dis[n];
    int s = rowptr[n], e = rowptr[n + 1];
    for (int j = s; j < e; j++)
        csr_w[j] = dis[csr_row[j]] * ew_csr[j] * dn;
}

// ---------------- weighted aggregation, MLP-optimized ----------------------
// One wave per node; each lane owns a bf16 PAIR (64 lanes x 4B = full 256B
// row per gather instruction). Edge loop manually unrolled x4 so each wave
// keeps 4 independent row-gathers in flight (the R8 version compiled to a
// 4-VGPR serial chain at 6% issue rate).
__global__ __launch_bounds__(128) void agg_kernel(
    const unsigned* __restrict__ xw32, const float* __restrict__ dis,
    const int* __restrict__ rowptr, const int* __restrict__ csr_row,
    const float* __restrict__ csr_w, const float* __restrict__ bias,
    __hip_bfloat16* __restrict__ out, int ldo)
{
    const int wv = threadIdx.x >> 6, lane = threadIdx.x & 63;
    const int n = blockIdx.x * 2 + wv;
    if (n >= NNODES) return;
    float dn = dis[n];
    unsigned v0 = xw32[(size_t)n * 64 + lane];
    float aL = dn * dn * __uint_as_float(v0 << 16);
    float aH = dn * dn * __uint_as_float(v0 & 0xffff0000u);
    int s = rowptr[n], e = rowptr[n + 1];
    int j = s;
    for (; j + 4 <= e; j += 4) {
        int r0 = csr_row[j], r1 = csr_row[j + 1];
        int r2 = csr_row[j + 2], r3 = csr_row[j + 3];
        float w0 = csr_w[j], w1 = csr_w[j + 1];
        float w2 = csr_w[j + 2], w3 = csr_w[j + 3];
        unsigned g0 = xw32[(size_t)r0 * 64 + lane];
        unsigned g1 = xw32[(size_t)r1 * 64 + lane];
        unsigned g2 = xw32[(size_t)r2 * 64 + lane];
        unsigned g3 = xw32[(size_t)r3 * 64 + lane];
        aL = fmaf(w0, __uint_as_float(g0 << 16), aL);
        aH = fmaf(w0, __uint_as_float(g0 & 0xffff0000u), aH);
        aL = fmaf(w1, __uint_as_float(g1 << 16), aL);
        aH = fmaf(w1, __uint_as_float(g1 & 0xffff0000u), aH);
        aL = fmaf(w2, __uint_as_float(g2 << 16), aL);
        aH = fmaf(w2, __uint_as_float(g2 & 0xffff0000u), aH);
        aL = fmaf(w3, __uint_as_float(g3 << 16), aL);
        aH = fmaf(w3, __uint_as_float(g3 & 0xffff0000u), aH);
    }
    for (; j < e; j++) {
        int r = csr_row[j];
        float w = csr_w[j];
        unsigned g = xw32[(size_t)r * 64 + lane];
        aL = fmaf(w, __uint_as_float(g << 16), aL);
        aH = fmaf(w, __uint_as_float(g & 0xffff0000u), aH);
    }
    float2 b = *(const float2*)(bias + 2 * lane);
    aL = fmaxf(aL + b.x, 0.f);
    aH = fmaxf(aH + b.y, 0.f);
    __hip_bfloat16 bl = __float2bfloat16(aL), bh = __float2bfloat16(aH);
    unsigned short ul, uh;
    memcpy(&ul, &bl, 2); memcpy(&uh, &bh, 2);
    unsigned o = (unsigned)ul | ((unsigned)uh << 16);
    *(unsigned*)(out + (size_t)n * ldo + 2 * lane) = o;
}

// ---------------- launch --------------------------------------------------
extern "C" void kernel_launch(void* const* d_in, const int* in_sizes, int n_in,
                              void* d_out, int out_size, void* d_ws, size_t ws_size,
                              hipStream_t stream)
{
    const float* x   = (const float*)d_in[0];
    const int*   ei  = (const int*)d_in[1];
    const float* Wp1 = (const float*)d_in[2];
    const float* bp1 = (const float*)d_in[3];
    const float* Wp2 = (const float*)d_in[4];
    const float* bp2 = (const float*)d_in[5];
    const float* Wp3 = (const float*)d_in[6];
    const float* bp3 = (const float*)d_in[7];
    const float* P0  = (const float*)d_in[8];
    const float* Wg0 = (const float*)d_in[9];
    const float* bg0 = (const float*)d_in[10];
    const float* Wg1 = (const float*)d_in[11];
    const float* bg1 = (const float*)d_in[12];
    // d_in[13], d_in[14] = Wg2/bg2: dead in reference
    const float* Wl1 = (const float*)d_in[15];
    const float* bl1 = (const float*)d_in[16];
    const float* Wl2 = (const float*)d_in[17];
    const float* bl2 = (const float*)d_in[18];
    float* out = (float*)d_out;

    char* wsb = (char*)d_ws;
    __hip_bfloat16* xb     = (__hip_bfloat16*)(wsb + XB_B);
    __hip_bfloat16* xj     = (__hip_bfloat16*)(wsb + XJ_B);
    __hip_bfloat16* hid    = (__hip_bfloat16*)(wsb + HID_B);
    __hip_bfloat16* h1     = (__hip_bfloat16*)(wsb + H1_B);
    __hip_bfloat16* xw     = (__hip_bfloat16*)(wsb + XW_B);
    __hip_bfloat16* h2     = (__hip_bfloat16*)(wsb + H2_B);
    __hip_bfloat16* lg     = (__hip_bfloat16*)(wsb + LG_B);
    __hip_bfloat16* pe     = (__hip_bfloat16*)(wsb + PE_B);
    int*            csr_row= (int*)(wsb + CSRR_B);
    float*          ew_csr = (float*)(wsb + EWC_B);
    int*            csr_col= (int*)(wsb + CSRW_B);   // overlays csr_w (dead until csrw_kernel)
    float*          csr_w  = (float*)(wsb + CSRW_B);
    int*            cnt    = (int*)(wsb + CNT_B);
    double*         S      = (double*)(wsb + S_B);
    int*            rowptr = (int*)(wsb + RP_B);
    int*            woff   = (int*)(wsb + WOFF_B);
    int*            incl   = (int*)(wsb + INCL_B);
    int*            bsum   = (int*)(wsb + BSUM_B);
    float*          st     = (float*)(wsb + ST_B);
    float*          dis    = (float*)(wsb + DIS_B);

    __hip_bfloat16* Wp1t = (__hip_bfloat16*)(wsb + WT_B + WP1T_O);
    __hip_bfloat16* Wg0t = (__hip_bfloat16*)(wsb + WT_B + WG0T_O);
    __hip_bfloat16* Wp2t = (__hip_bfloat16*)(wsb + WT_B + WP2T_O);
    __hip_bfloat16* Wp3t = (__hip_bfloat16*)(wsb + WT_B + WP3T_O);
    __hip_bfloat16* W2t  = (__hip_bfloat16*)(wsb + WT_B + W2T_O);
    __hip_bfloat16* Wg1t = (__hip_bfloat16*)(wsb + WT_B + WG1T_O);
    __hip_bfloat16* Wl1t = (__hip_bfloat16*)(wsb + WT_B + WL1T_O);
    __hip_bfloat16* Wl2t = (__hip_bfloat16*)(wsb + WT_B + WL2T_O);
    float*          bias_g1 = (float*)(wsb + WT_B + BG1_O);
    float*          bias_g3 = (float*)(wsb + WT_B + BG3_O);

    const int EB = (NEDGES + 255) / 256;            // 3125
    const int NB = (NNODES + 255) / 256;            // 196
    const int MT = (NNODES + 127) / 128;            // 391 row tiles
    const int BIGN = 1 << 30;

    hipMemsetAsync(wsb + CNT_B, 0, ZERO_BYTES, stream);

    // --- prep: weight transpose+cast, fused Wp3@P fold, x cast ---
    WP wp;
    wp.w[0] = { Wp1, Wp1t, 512, 512 };
    wp.w[1] = { Wg0, Wg0t, 512, 128 };
    wp.w[2] = { Wp2, Wp2t, 512,  64 };
    wp.w[3] = { Wp3, Wp3t,  64,  64 };
    wp.w[4] = { Wg1, Wg1t, 128, 128 };
    wp.w[5] = { Wl1, Wl1t, 256, 128 };
    wp.w[6] = { Wl2, Wl2t, 128,  64 };
    transpose_cast_all<<<dim3(1024, 7), 256, 0, stream>>>(wp);
    combine_p0<<<20, 256, 0, stream>>>(Wp3, bp3, P0, bp1, W2t, bias_g1, bias_g3);
    cast_x_kernel<<<12500, 256, 0, stream>>>(x, xb, (long)NNODES * IND);

    // --- CSR build (indices only; independent of ew) ---
    count_kernel<<<EB, 256, 0, stream>>>(ei, cnt);
    scan1_kernel<<<NB, 256, 0, stream>>>(cnt, incl, bsum);
    scan2_kernel<<<1, 256, 0, stream>>>(bsum, NB);
    scan3_kernel<<<NB, 256, 0, stream>>>(cnt, incl, bsum, rowptr, woff);
    scatter_idx_kernel<<<EB, 256, 0, stream>>>(ei, woff, csr_row, csr_col);

    // --- fused G1: [h1 | xw] = xb @ [Wp1 | Wg0]^T ---
    gemm_mfma<128, 64><<<dim3(5, MT), 256, 0, stream>>>(
        xb, 512, Wp1t, 512, bias_g1, h1, 512, xw, 128, 512, NNODES, 512, 1, 1);

    // --- G2: h2 = relu(h1 @ Wp2 + bp2) ---
    gemm_mfma<64, 32><<<dim3(1, MT), 256, 0, stream>>>(
        h1, 512, Wp2t, 512, bp2, h2, 64, nullptr, 0, BIGN, NNODES, 512, 1, 1);

    // --- fused G3: [lg | pe] = h2 @ [Wp3 | Wp3@P]^T + [bp3 | bp3@P] ---
    gemm_mfma<128, 64><<<dim3(1, MT), 256, 0, stream>>>(
        h2, 64, Wp3t, 64, bias_g3, lg, 64, pe, 64, 64, NNODES, 64, 0, 1);

    // --- per-edge weights (8-lane cooperative) + stats ---
    edge_ew_gather<<<(NEDGES + 31) / 32, 256, 0, stream>>>(lg, pe, csr_row, csr_col, ew_csr);
    ew_stats_kernel<<<512, 256, 0, stream>>>(ew_csr, S);
    stats_kernel<<<1, 1, 0, stream>>>(S, st);
    norm_deg_kernel<<<NB, 256, 0, stream>>>(rowptr, ew_csr, st, dis);
    csrw_kernel<<<NB, 256, 0, stream>>>(rowptr, csr_row, ew_csr, dis, csr_w);

    // --- GCN layer 0 aggregation (xw from fused G1) ---
    agg_kernel<<<25000, 128, 0, stream>>>((const unsigned*)xw, dis, rowptr, csr_row, csr_w, bg0, xj, 2 * HD);

    // --- GCN layer 1 ---
    gemm_mfma<64, 32><<<dim3(2, MT), 256, 0, stream>>>(
        xj, 2 * HD, Wg1t, 128, nullptr, xw, 128, nullptr, 0, BIGN, NNODES, 128, 0, 1);
    agg_kernel<<<25000, 128, 0, stream>>>((const unsigned*)xw, dis, rowptr, csr_row, csr_w, bg1, xj + HD, 2 * HD);

    // --- JK head ---
    gemm_mfma<128, 64><<<dim3(1, MT), 256, 0, stream>>>(
        xj, 2 * HD, Wl1t, 256, bl1, hid, 128, nullptr, 0, BIGN, NNODES, 256, 1, 1);
    gemm_mfma<64, 32><<<dim3(1, MT), 256, 0, stream>>>(
        hid, 128, Wl2t, 128, bl2, out, 64, nullptr, 0, BIGN, NNODES, 128, 0, 0);
}

// Round 11
// 573.254 us; speedup vs baseline: 1.6650x; 1.0059x over previous
//
#include <hip/hip_runtime.h>
#include <hip/hip_bf16.h>
#include <cmath>
#include <cstring>

#define NNODES 50000
#define NEDGES 800000
#define IND    512
#define HD     128
#define CD     64

typedef __bf16 bf16x8 __attribute__((ext_vector_type(8)));
typedef float  f32x4  __attribute__((ext_vector_type(4)));
typedef const __attribute__((address_space(1))) unsigned int* gu32p;
typedef __attribute__((address_space(3))) unsigned int* lu32p;

// ---------------- workspace layout (byte offsets) ----------------
static const size_t XJ_B   = 0;           // bf16 50000x256
static const size_t HID_B  = 25600000;    // bf16 50000x128 (JK head, late)
static const size_t H1_B   = 51200000;    // bf16 50000x512
static const size_t XW_B   = 102400000;   // bf16 50000x128
static const size_t H2_B   = 115200000;   // bf16 50000x64
static const size_t LG_B   = 121600000;   // bf16 50000x64
static const size_t PE_B   = 128000000;   // bf16 50000x64
static const size_t WT_B   = 134400000;   // transposed bf16 weights + biases (~0.9MB)
static const size_t CSRR_B = 135300000;   // int 800000 (csr row index)
static const size_t EWC_B  = 138500000;   // fp32 800000 (ew in CSR order; normalized in place)
// csr_col overlays csr_w: csr_col written by scatter, last read by edge_ew_gather;
// csr_w first written by csrw_kernel which runs strictly AFTER edge_ew_gather.
static const size_t CSRW_B = 141700000;   // int csr_col -> then fp32 csr_w
static const size_t CNT_B  = 144900000;   // int 50000   (zero block start)
static const size_t S_B    = 145100000;   // 2 doubles
static const size_t ZERO_BYTES = 200016;  // cnt + S
static const size_t RP_B   = 145100016;   // int 50001
static const size_t WOFF_B = 145300020;   // int 50000
static const size_t INCL_B = 145500020;   // int 50000
static const size_t BSUM_B = 145700020;   // int 256
static const size_t ST_B   = 145701044;   // 2 floats
static const size_t DIS_B  = 145701052;   // fp32 50000
// total ~145.9 MB

// weight sub-offsets (bytes within WT_B). Wp1t then Wg0t CONTIGUOUS (G1 fused
// Bt [640,512]); Wp3t then W2t=(Wp3@P)t CONTIGUOUS (G3 fused Bt [128,64]).
static const size_t WP1T_O = 0;       // 512x512
static const size_t WG0T_O = 524288;  // 128x512
static const size_t WP2T_O = 655360;  // 64x512
static const size_t WP3T_O = 720896;  // 64x64
static const size_t W2T_O  = 729088;  // 64x64 (Wp3 @ relu(2*P0), transposed)
static const size_t WG1T_O = 737280;  // 128x128
static const size_t WL1T_O = 770048;  // 128x256
static const size_t WL2T_O = 835584;  // 64x128
static const size_t BG1_O  = 851968;  // fp32 640: [bp1 | zeros(128)]
static const size_t BG3_O  = 854528;  // fp32 128: [bp3 | bp3@P]

// ---------------- weight transpose+cast: dst[n*K+k] = cvt(src[k*N+n]) ------
struct WD { const float* s; __hip_bfloat16* d; int K; int N; };
struct WP { WD w[7]; };

__global__ __launch_bounds__(256) void transpose_cast_all(WP p)
{
    WD d = p.w[blockIdx.y];
    int i = blockIdx.x * 256 + threadIdx.x;
    if (i >= d.K * d.N) return;
    int k = i % d.K, n = i / d.K;
    d.d[i] = __float2bfloat16(d.s[(size_t)k * d.N + n]);
}

// ---------------- prep: W2t = (Wp3 @ relu(2*P0))^T, bias concats -----------
__global__ __launch_bounds__(256) void combine_p0(
    const float* __restrict__ Wp3, const float* __restrict__ bp3,
    const float* __restrict__ P0, const float* __restrict__ bp1,
    __hip_bfloat16* __restrict__ W2t, float* __restrict__ bias_g1,
    float* __restrict__ bias_g3)
{
    int b = blockIdx.x;
    if (b < 16) {
        int i = b * 256 + threadIdx.x;   // k = i>>6, n = i&63
        int k = i >> 6, n = i & 63;
        float s = 0.f;
        for (int j = 0; j < 64; j++)
            s += Wp3[k * 64 + j] * fmaxf(2.f * P0[j * 64 + n], 0.f);
        W2t[n * 64 + k] = __float2bfloat16(s);
    } else if (b == 16) {
        int n = threadIdx.x;
        if (n < 64) {
            float s = 0.f;
            for (int j = 0; j < 64; j++)
                s += bp3[j] * fmaxf(2.f * P0[j * 64 + n], 0.f);
            bias_g3[n] = bp3[n];
            bias_g3[64 + n] = s;
        }
    } else {
        int i = (b - 17) * 256 + threadIdx.x;   // 0..767
        if (i < 512) bias_g1[i] = bp1[i];
        else if (i < 640) bias_g1[i] = 0.f;
    }
}

// ---------------- bf16 MFMA GEMM: C = act(A[M,K] @ Bt[N,K]^T + bias) -------
// BM=128, 4 waves, wave tile 64 x WN, BN = 2*WN. K%32==0, N%BN==0.
// CAST_A=0: A staged via global_load_lds (width 16) into unpadded [row][32]
//   tiles with XOR chunk swizzle (chunk' = chunk ^ (row&3)) -> LDS reads hit
//   8 banks x 2 lanes (2-way aliasing = free).
// CAST_A=1: A is fp32; staged via float4 load + cvt + ds_write into a PADDED
//   stride-40 tile (row index clamped to M-1: input buffer has no slack).
// B always global_load_lds + swizzle. Blocks XCD-swizzled (NC col-tiles of a
// row strip share lin%8). splitN: cols >= splitN -> Cout2 (bf16, no relu);
// bias applied to ALL cols (pad bias arrays with zeros where none wanted).
template<int BN, int WN, int CAST_A>
__global__ __launch_bounds__(256) void gemm_mfma(
    const void* __restrict__ Ap, int lda,
    const __hip_bfloat16* __restrict__ Bt, int ldb,
    const float* __restrict__ bias,
    void* __restrict__ Cout, int ldc,
    void* __restrict__ Cout2, int ldc2, int splitN,
    int M, int K, int do_relu, int out_bf16)
{
    constexpr int BF = WN / 16;
    constexpr int BPASS = BN / 64;
    constexpr int AST = CAST_A ? 40 : 32;
    __shared__ __bf16 As[128 * AST];
    __shared__ __bf16 Bs[BN * 32];

    const int NC = gridDim.x, NR = gridDim.y;
    int g = blockIdx.y * NC + blockIdx.x;
    int per = NC * 8;
    int nfull = (NR >> 3) * per;
    int rowt, colt;
    if (g < nfull) {
        int grp = g / per, rem = g % per;
        rowt = grp * 8 + (rem & 7);
        colt = rem >> 3;
    } else {
        int rem = g - nfull;
        int tail = NR - (NR >> 3) * 8;
        rowt = (NR >> 3) * 8 + rem % tail;
        colt = rem / tail;
    }

    const int t = threadIdx.x;
    const int row0 = rowt * 128;
    const int col0 = colt * BN;

    const int wv   = t >> 6;
    const int lane = t & 63;
    const int quad = lane >> 4;
    const int l16  = lane & 15;
    const int wrow = (wv >> 1) * 64;
    const int wcol = (wv & 1) * WN;

    const int subrow = lane >> 2;                          // 0..15
    const int kchunk = (lane & 3) ^ (subrow & 3);          // swizzled chunk
    const int subkg  = kchunk * 8;

    f32x4 acc[4][BF] = {};

    for (int k0 = 0; k0 < K; k0 += 32) {
        if (CAST_A) {
            const float* Af = (const float*)Ap;
            #pragma unroll
            for (int p = 0; p < 4; p++) {
                int idx = t + p * 256;
                int r = idx >> 3, kg = (idx & 7) * 4;
                int m = row0 + r;
                if (m > M - 1) m = M - 1;   // clamp: input has no slack
                float4 v = *(const float4*)(Af + (size_t)m * lda + k0 + kg);
                __hip_bfloat16 o[4] __attribute__((aligned(8)));
                o[0] = __float2bfloat16(v.x); o[1] = __float2bfloat16(v.y);
                o[2] = __float2bfloat16(v.z); o[3] = __float2bfloat16(v.w);
                *(int2*)&As[r * AST + kg] = *(const int2*)o;
            }
        } else {
            const __hip_bfloat16* Ab = (const __hip_bfloat16*)Ap;
            #pragma unroll
            for (int p = 0; p < 2; p++) {
                int rowA = (p * 4 + wv) * 16 + subrow;
                const __hip_bfloat16* gp = Ab + (size_t)(row0 + rowA) * lda + k0 + subkg;
                __builtin_amdgcn_global_load_lds((gu32p)(const void*)gp,
                    (lu32p)(void*)&As[(p * 4 + wv) * 512], 16, 0, 0);
            }
        }
        #pragma unroll
        for (int p = 0; p < BPASS; p++) {
            int rowB = (p * 4 + wv) * 16 + subrow;
            const __hip_bfloat16* gp = Bt + (size_t)(col0 + rowB) * ldb + k0 + subkg;
            __builtin_amdgcn_global_load_lds((gu32p)(const void*)gp,
                (lu32p)(void*)&Bs[(p * 4 + wv) * 512], 16, 0, 0);
        }
        __syncthreads();

        bf16x8 af[4], bfr[BF];
        #pragma unroll
        for (int i = 0; i < 4; i++) {
            int R = wrow + i * 16 + l16;
            int c = CAST_A ? quad : (quad ^ (R & 3));
            af[i] = *(const bf16x8*)&As[R * AST + c * 8];
        }
        #pragma unroll
        for (int j = 0; j < BF; j++) {
            int R = wcol + j * 16 + l16;
            bfr[j] = *(const bf16x8*)&Bs[R * 32 + (quad ^ (R & 3)) * 8];
        }
        #pragma unroll
        for (int i = 0; i < 4; i++)
            #pragma unroll
            for (int j = 0; j < BF; j++)
                acc[i][j] = __builtin_amdgcn_mfma_f32_16x16x32_bf16(af[i], bfr[j], acc[i][j], 0, 0, 0);
        __syncthreads();
    }

    #pragma unroll
    for (int i = 0; i < 4; i++) {
        #pragma unroll
        for (int j = 0; j < BF; j++) {
            int n = col0 + wcol + j * 16 + l16;
            bool second = (n >= splitN);
            float bv = bias ? bias[n] : 0.f;
            #pragma unroll
            for (int reg = 0; reg < 4; reg++) {
                int m = row0 + wrow + i * 16 + quad * 4 + reg;
                if (m >= M) continue;
                float v = acc[i][j][reg] + bv;
                if (do_relu && !second) v = fmaxf(v, 0.f);
                if (second)
                    ((__hip_bfloat16*)Cout2)[(size_t)m * ldc2 + (n - splitN)] = __float2bfloat16(v);
                else if (out_bf16)
                    ((__hip_bfloat16*)Cout)[(size_t)m * ldc + n] = __float2bfloat16(v);
                else
                    ((float*)Cout)[(size_t)m * ldc + n] = v;
            }
        }
    }
}

// ---------------- CSR build (indices only) ---------------------------------
__global__ __launch_bounds__(256) void count_kernel(
    const int* __restrict__ ei, int* __restrict__ cnt)
{
    int e = blockIdx.x * 256 + threadIdx.x;
    if (e >= NEDGES) return;
    atomicAdd(&cnt[ei[NEDGES + e]], 1);
}

__global__ __launch_bounds__(256) void scan1_kernel(
    const int* __restrict__ cnt, int* __restrict__ incl, int* __restrict__ bsum)
{
    __shared__ int s[256];
    int t = threadIdx.x;
    int i = blockIdx.x * 256 + t;
    int v = (i < NNODES) ? cnt[i] : 0;
    s[t] = v;
    __syncthreads();
    for (int off = 1; off < 256; off <<= 1) {
        int u = (t >= off) ? s[t - off] : 0;
        __syncthreads();
        s[t] += u;
        __syncthreads();
    }
    if (i < NNODES) incl[i] = s[t];
    if (t == 255) bsum[blockIdx.x] = s[255];
}

__global__ __launch_bounds__(256) void scan2_kernel(int* __restrict__ bsum, int nb)
{
    __shared__ int s[256];
    int t = threadIdx.x;
    int v = (t < nb) ? bsum[t] : 0;
    s[t] = v;
    __syncthreads();
    for (int off = 1; off < 256; off <<= 1) {
        int u = (t >= off) ? s[t - off] : 0;
        __syncthreads();
        s[t] += u;
        __syncthreads();
    }
    if (t < nb) bsum[t] = s[t] - v;   // exclusive block offset
}

__global__ __launch_bounds__(256) void scan3_kernel(
    const int* __restrict__ cnt, const int* __restrict__ incl,
    const int* __restrict__ bsum, int* __restrict__ rowptr, int* __restrict__ woff)
{
    int i = blockIdx.x * 256 + threadIdx.x;
    if (i >= NNODES) return;
    int off = bsum[blockIdx.x];
    int r = incl[i] - cnt[i] + off;
    rowptr[i] = r;
    woff[i] = r;
    if (i == NNODES - 1) rowptr[NNODES] = incl[i] + off;
}

__global__ __launch_bounds__(256) void scatter_idx_kernel(
    const int* __restrict__ ei, int* __restrict__ woff,
    int* __restrict__ csr_row, int* __restrict__ csr_col)
{
    int e = blockIdx.x * 256 + threadIdx.x;
    if (e >= NEDGES) return;
    int r = ei[e];
    int c = ei[NEDGES + e];
    int p = atomicAdd(&woff[c], 1);
    csr_row[p] = r;
    csr_col[p] = c;
}

// ---------------- edge weight: 8 lanes cooperate per edge ------------------
__global__ __launch_bounds__(256) void edge_ew_gather(
    const __hip_bfloat16* __restrict__ lg, const __hip_bfloat16* __restrict__ pe,
    const int* __restrict__ csr_row, const int* __restrict__ csr_col,
    float* __restrict__ ew_csr)
{
    const int tid = threadIdx.x;
    const int sub = tid & 7;
    const int e = blockIdx.x * 32 + (tid >> 3);
    if (e >= NEDGES) return;
    int r = csr_row[e];
    int c = csr_col[e];
    bf16x8 a = *(const bf16x8*)(lg + (size_t)r * CD + sub * 8);
    bf16x8 b = *(const bf16x8*)(pe + (size_t)c * CD + sub * 8);
    float acc = 0.f;
    #pragma unroll
    for (int u = 0; u < 8; u++)
        acc += (float)a[u] * (float)b[u];
    acc += __shfl_xor(acc, 1);
    acc += __shfl_xor(acc, 2);
    acc += __shfl_xor(acc, 4);
    if (sub == 0) ew_csr[e] = acc;
}

// grid-stride stats over the dense ew array (sequential read, ~3.2MB)
__global__ __launch_bounds__(256) void ew_stats_kernel(
    const float* __restrict__ ew, double* __restrict__ S)
{
    const int tid = threadIdx.x;
    double s1 = 0.0, s2 = 0.0;
    for (int i = blockIdx.x * 256 + tid; i < NEDGES; i += gridDim.x * 256) {
        float v = ew[i];
        s1 += v; s2 += (double)v * (double)v;
    }
    __shared__ double sh1[256], sh2[256];
    sh1[tid] = s1; sh2[tid] = s2;
    __syncthreads();
    for (int s = 128; s > 0; s >>= 1) {
        if (tid < s) { sh1[tid] += sh1[tid + s]; sh2[tid] += sh2[tid + s]; }
        __syncthreads();
    }
    if (tid == 0) {
        atomicAdd(&S[0], sh1[0]);
        atomicAdd(&S[1], sh2[0]);
    }
}

__global__ void stats_kernel(const double* __restrict__ S, float* __restrict__ st)
{
    double E = (double)NEDGES;
    double mean = S[0] / E;
    double var = (S[1] - S[0] * S[0] / E) / (E - 1.0);
    st[0] = (float)mean;
    st[1] = (float)sqrt(1e-4 / var);
}

// per node: normalize segment in place, deg = segment sum, dis = rsqrt(deg+1)
__global__ __launch_bounds__(256) void norm_deg_kernel(
    const int* __restrict__ rowptr, float* __restrict__ ew_csr,
    const float* __restrict__ st, float* __restrict__ dis)
{
    int n = blockIdx.x * 256 + threadIdx.x;
    if (n >= NNODES) return;
    float mean = st[0], alpha = st[1];
    int s = rowptr[n], e = rowptr[n + 1];
    float sum = 0.f;
    for (int j = s; j < e; j++) {
        float w = (ew_csr[j] - mean) * alpha + 1.0f;
        ew_csr[j] = w;
        sum += w;
    }
    float d = sum + 1.0f;                       // self-loop weight 1
    dis[n] = (d > 0.f) ? rsqrtf(d) : 0.f;
}

// per node: csr_w[j] = dis[row]*w*dis[n]  (csr_w overlays the dead csr_col)
__global__ __launch_bounds__(256) void csrw_kernel(
    const int* __restrict__ rowptr, const int* __restrict__ csr_row,
    const float* __restrict__ ew_csr, const float* __restrict__ dis,
    float* __restrict__ csr_w)
{
    int n = blockIdx.x * 256 + threadIdx.x;
    if (n >= NNODES) return;
    float dn = dis[n];
    int s = rowptr[n], e = rowptr[n + 1];
    for (int j = s; j < e; j++)
        csr_w[j] = dis[csr_row[j]] * ew_csr[j] * dn;
}

// ---------------- weighted aggregation, MLP-optimized ----------------------
// One wave per node; each lane owns a bf16 PAIR (64 lanes x 4B = full 256B
// row per gather instruction). Edge loop manually unrolled x4 so each wave
// keeps 4 independent row-gathers in flight.
__global__ __launch_bounds__(128) void agg_kernel(
    const unsigned* __restrict__ xw32, const float* __restrict__ dis,
    const int* __restrict__ rowptr, const int* __restrict__ csr_row,
    const float* __restrict__ csr_w, const float* __restrict__ bias,
    __hip_bfloat16* __restrict__ out, int ldo)
{
    const int wv = threadIdx.x >> 6, lane = threadIdx.x & 63;
    const int n = blockIdx.x * 2 + wv;
    if (n >= NNODES) return;
    float dn = dis[n];
    unsigned v0 = xw32[(size_t)n * 64 + lane];
    float aL = dn * dn * __uint_as_float(v0 << 16);
    float aH = dn * dn * __uint_as_float(v0 & 0xffff0000u);
    int s = rowptr[n], e = rowptr[n + 1];
    int j = s;
    for (; j + 4 <= e; j += 4) {
        int r0 = csr_row[j], r1 = csr_row[j + 1];
        int r2 = csr_row[j + 2], r3 = csr_row[j + 3];
        float w0 = csr_w[j], w1 = csr_w[j + 1];
        float w2 = csr_w[j + 2], w3 = csr_w[j + 3];
        unsigned g0 = xw32[(size_t)r0 * 64 + lane];
        unsigned g1 = xw32[(size_t)r1 * 64 + lane];
        unsigned g2 = xw32[(size_t)r2 * 64 + lane];
        unsigned g3 = xw32[(size_t)r3 * 64 + lane];
        aL = fmaf(w0, __uint_as_float(g0 << 16), aL);
        aH = fmaf(w0, __uint_as_float(g0 & 0xffff0000u), aH);
        aL = fmaf(w1, __uint_as_float(g1 << 16), aL);
        aH = fmaf(w1, __uint_as_float(g1 & 0xffff0000u), aH);
        aL = fmaf(w2, __uint_as_float(g2 << 16), aL);
        aH = fmaf(w2, __uint_as_float(g2 & 0xffff0000u), aH);
        aL = fmaf(w3, __uint_as_float(g3 << 16), aL);
        aH = fmaf(w3, __uint_as_float(g3 & 0xffff0000u), aH);
    }
    for (; j < e; j++) {
        int r = csr_row[j];
        float w = csr_w[j];
        unsigned g = xw32[(size_t)r * 64 + lane];
        aL = fmaf(w, __uint_as_float(g << 16), aL);
        aH = fmaf(w, __uint_as_float(g & 0xffff0000u), aH);
    }
    float2 b = *(const float2*)(bias + 2 * lane);
    aL = fmaxf(aL + b.x, 0.f);
    aH = fmaxf(aH + b.y, 0.f);
    __hip_bfloat16 bl = __float2bfloat16(aL), bh = __float2bfloat16(aH);
    unsigned short ul, uh;
    memcpy(&ul, &bl, 2); memcpy(&uh, &bh, 2);
    unsigned o = (unsigned)ul | ((unsigned)uh << 16);
    *(unsigned*)(out + (size_t)n * ldo + 2 * lane) = o;
}

// ---------------- launch --------------------------------------------------
extern "C" void kernel_launch(void* const* d_in, const int* in_sizes, int n_in,
                              void* d_out, int out_size, void* d_ws, size_t ws_size,
                              hipStream_t stream)
{
    const float* x   = (const float*)d_in[0];
    const int*   ei  = (const int*)d_in[1];
    const float* Wp1 = (const float*)d_in[2];
    const float* bp1 = (const float*)d_in[3];
    const float* Wp2 = (const float*)d_in[4];
    const float* bp2 = (const float*)d_in[5];
    const float* Wp3 = (const float*)d_in[6];
    const float* bp3 = (const float*)d_in[7];
    const float* P0  = (const float*)d_in[8];
    const float* Wg0 = (const float*)d_in[9];
    const float* bg0 = (const float*)d_in[10];
    const float* Wg1 = (const float*)d_in[11];
    const float* bg1 = (const float*)d_in[12];
    // d_in[13], d_in[14] = Wg2/bg2: dead in reference
    const float* Wl1 = (const float*)d_in[15];
    const float* bl1 = (const float*)d_in[16];
    const float* Wl2 = (const float*)d_in[17];
    const float* bl2 = (const float*)d_in[18];
    float* out = (float*)d_out;

    char* wsb = (char*)d_ws;
    __hip_bfloat16* xj     = (__hip_bfloat16*)(wsb + XJ_B);
    __hip_bfloat16* hid    = (__hip_bfloat16*)(wsb + HID_B);
    __hip_bfloat16* h1     = (__hip_bfloat16*)(wsb + H1_B);
    __hip_bfloat16* xw     = (__hip_bfloat16*)(wsb + XW_B);
    __hip_bfloat16* h2     = (__hip_bfloat16*)(wsb + H2_B);
    __hip_bfloat16* lg     = (__hip_bfloat16*)(wsb + LG_B);
    __hip_bfloat16* pe     = (__hip_bfloat16*)(wsb + PE_B);
    int*            csr_row= (int*)(wsb + CSRR_B);
    float*          ew_csr = (float*)(wsb + EWC_B);
    int*            csr_col= (int*)(wsb + CSRW_B);   // overlays csr_w (dead until csrw_kernel)
    float*          csr_w  = (float*)(wsb + CSRW_B);
    int*            cnt    = (int*)(wsb + CNT_B);
    double*         S      = (double*)(wsb + S_B);
    int*            rowptr = (int*)(wsb + RP_B);
    int*            woff   = (int*)(wsb + WOFF_B);
    int*            incl   = (int*)(wsb + INCL_B);
    int*            bsum   = (int*)(wsb + BSUM_B);
    float*          st     = (float*)(wsb + ST_B);
    float*          dis    = (float*)(wsb + DIS_B);

    __hip_bfloat16* Wp1t = (__hip_bfloat16*)(wsb + WT_B + WP1T_O);
    __hip_bfloat16* Wg0t = (__hip_bfloat16*)(wsb + WT_B + WG0T_O);
    __hip_bfloat16* Wp2t = (__hip_bfloat16*)(wsb + WT_B + WP2T_O);
    __hip_bfloat16* Wp3t = (__hip_bfloat16*)(wsb + WT_B + WP3T_O);
    __hip_bfloat16* W2t  = (__hip_bfloat16*)(wsb + WT_B + W2T_O);
    __hip_bfloat16* Wg1t = (__hip_bfloat16*)(wsb + WT_B + WG1T_O);
    __hip_bfloat16* Wl1t = (__hip_bfloat16*)(wsb + WT_B + WL1T_O);
    __hip_bfloat16* Wl2t = (__hip_bfloat16*)(wsb + WT_B + WL2T_O);
    float*          bias_g1 = (float*)(wsb + WT_B + BG1_O);
    float*          bias_g3 = (float*)(wsb + WT_B + BG3_O);

    const int EB = (NEDGES + 255) / 256;            // 3125
    const int NB = (NNODES + 255) / 256;            // 196
    const int MT = (NNODES + 127) / 128;            // 391 row tiles
    const int BIGN = 1 << 30;

    hipMemsetAsync(wsb + CNT_B, 0, ZERO_BYTES, stream);

    // --- prep: weight transpose+cast, fused Wp3@P fold ---
    WP wp;
    wp.w[0] = { Wp1, Wp1t, 512, 512 };
    wp.w[1] = { Wg0, Wg0t, 512, 128 };
    wp.w[2] = { Wp2, Wp2t, 512,  64 };
    wp.w[3] = { Wp3, Wp3t,  64,  64 };
    wp.w[4] = { Wg1, Wg1t, 128, 128 };
    wp.w[5] = { Wl1, Wl1t, 256, 128 };
    wp.w[6] = { Wl2, Wl2t, 128,  64 };
    transpose_cast_all<<<dim3(1024, 7), 256, 0, stream>>>(wp);
    combine_p0<<<20, 256, 0, stream>>>(Wp3, bp3, P0, bp1, W2t, bias_g1, bias_g3);

    // --- CSR build (indices only; independent of ew) ---
    count_kernel<<<EB, 256, 0, stream>>>(ei, cnt);
    scan1_kernel<<<NB, 256, 0, stream>>>(cnt, incl, bsum);
    scan2_kernel<<<1, 256, 0, stream>>>(bsum, NB);
    scan3_kernel<<<NB, 256, 0, stream>>>(cnt, incl, bsum, rowptr, woff);
    scatter_idx_kernel<<<EB, 256, 0, stream>>>(ei, woff, csr_row, csr_col);

    // --- fused G1: [h1 | xw] = x @ [Wp1 | Wg0]^T (fp32 A cast in staging) ---
    gemm_mfma<128, 64, 1><<<dim3(5, MT), 256, 0, stream>>>(
        x, 512, Wp1t, 512, bias_g1, h1, 512, xw, 128, 512, NNODES, 512, 1, 1);

    // --- G2: h2 = relu(h1 @ Wp2 + bp2) ---
    gemm_mfma<64, 32, 0><<<dim3(1, MT), 256, 0, stream>>>(
        h1, 512, Wp2t, 512, bp2, h2, 64, nullptr, 0, BIGN, NNODES, 512, 1, 1);

    // --- fused G3: [lg | pe] = h2 @ [Wp3 | Wp3@P]^T + [bp3 | bp3@P] ---
    gemm_mfma<128, 64, 0><<<dim3(1, MT), 256, 0, stream>>>(
        h2, 64, Wp3t, 64, bias_g3, lg, 64, pe, 64, 64, NNODES, 64, 0, 1);

    // --- per-edge weights (8-lane cooperative) + stats ---
    edge_ew_gather<<<(NEDGES + 31) / 32, 256, 0, stream>>>(lg, pe, csr_row, csr_col, ew_csr);
    ew_stats_kernel<<<512, 256, 0, stream>>>(ew_csr, S);
    stats_kernel<<<1, 1, 0, stream>>>(S, st);
    norm_deg_kernel<<<NB, 256, 0, stream>>>(rowptr, ew_csr, st, dis);
    csrw_kernel<<<NB, 256, 0, stream>>>(rowptr, csr_row, ew_csr, dis, csr_w);

    // --- GCN layer 0 aggregation (xw from fused G1) ---
    agg_kernel<<<25000, 128, 0, stream>>>((const unsigned*)xw, dis, rowptr, csr_row, csr_w, bg0, xj, 2 * HD);

    // --- GCN layer 1 ---
    gemm_mfma<64, 32, 0><<<dim3(2, MT), 256, 0, stream>>>(
        xj, 2 * HD, Wg1t, 128, nullptr, xw, 128, nullptr, 0, BIGN, NNODES, 128, 0, 1);
    agg_kernel<<<25000, 128, 0, stream>>>((const unsigned*)xw, dis, rowptr, csr_row, csr_w, bg1, xj + HD, 2 * HD);

    // --- JK head ---
    gemm_mfma<128, 64, 0><<<dim3(1, MT), 256, 0, stream>>>(
        xj, 2 * HD, Wl1t, 256, bl1, hid, 128, nullptr, 0, BIGN, NNODES, 256, 1, 1);
    gemm_mfma<64, 32, 0><<<dim3(1, MT), 256, 0, stream>>>(
        hid, 128, Wl2t, 128, bl2, out, 64, nullptr, 0, BIGN, NNODES, 128, 0, 0);
}